// Round 10
// baseline (3282.159 us; speedup 1.0000x reference)
//
#include <hip/hip_runtime.h>
#include <hip/hip_bf16.h>

#define HW 4096
#define WD 64
#define HT 64
#define NEGV -1000000000.0f

typedef const void* vp;
typedef __attribute__((ext_vector_type(8))) short bf16x8;
typedef __attribute__((ext_vector_type(8))) unsigned short ushort8;
typedef __attribute__((ext_vector_type(4))) float f32x4;

__device__ __forceinline__ float b2f(__hip_bfloat16 v){ return __bfloat162float(v); }
__device__ __forceinline__ float ldf(vp p, size_t i, int f){
  return f ? ((const float*)p)[i] : b2f(((const __hip_bfloat16*)p)[i]);
}
__device__ __forceinline__ unsigned short f2b(float x){
  __hip_bfloat16 h = __float2bfloat16(x);
  return *reinterpret_cast<unsigned short*>(&h);
}
__device__ __forceinline__ float u2f(unsigned short u){
  union { unsigned int i; float f; } x; x.i = ((unsigned int)u) << 16; return x.f;
}
__device__ __forceinline__ float4 ld4(vp p, size_t i, int f){
  if(f) return *(const float4*)((const float*)p + i);
  ushort4 u = *(const ushort4*)((const unsigned short*)p + i);
  return make_float4(u2f(u.x), u2f(u.y), u2f(u.z), u2f(u.w));
}

// LDS conv-tile swizzle: 64-ushort rows (8x16B blocks), block XOR keyed on
// (row ^ row>>3)&7.
__device__ __forceinline__ int swz(int row, int blk){
  return row*64 + (((blk ^ ((row ^ (row>>3)) & 7)) << 3));
}

// ---------- dtype detector ----------
__global__ void k_detect(int* flag, const unsigned short* p){
  __shared__ int cnt;
  if(threadIdx.x==0) cnt=0;
  __syncthreads();
  int c=0;
  for(int i=threadIdx.x; i<512; i+=256){
    int e = (p[i]>>7)&0xFF;
    if(e>150 || e<100) c++;
  }
  atomicAdd(&cnt, c);
  __syncthreads();
  if(threadIdx.x==0) *flag = (cnt>32) ? 1 : 0;  // 1 = fp32 inputs
}

// ---------- elementwise (vectorized x4) ----------
__global__ void k_cvt(float4* dst, vp src, int n4, const int* dflag){
  int f = *dflag;
  int i = blockIdx.x*256 + threadIdx.x;
  if(i<n4) dst[i] = ld4(src, (size_t)i*4, f);
}

__global__ void k_zero(float* p, int n){
  int i = blockIdx.x*256 + threadIdx.x;
  if(i<n) p[i] = 0.f;
}

// ---------- fused token transpose + memory_2d output write ----------
__global__ __launch_bounds__(256) void k_finalize_mem(
    float* __restrict__ mem_t, void* __restrict__ dout,
    const float* __restrict__ memf, const int* dflag)
{
  __shared__ float tile[64][65];
  const int f = *dflag;
  const int tid = threadIdx.x;
  const int s0 = blockIdx.x*64, c0t = blockIdx.y*64, b = blockIdx.z;
  const int sl = tid & 63, g4 = tid >> 6;
  #pragma unroll
  for(int p=0; p<16; p++){
    int cl = p*4 + g4;
    float v = memf[((size_t)(b*256 + c0t + cl))*HW + s0 + sl];
    tile[sl][cl] = v;
    size_t o = 102400 + ((size_t)(b*256 + c0t + cl))*HW + s0 + sl;
    if(f) ((float*)dout)[o] = v;
    else  ((__hip_bfloat16*)dout)[o] = __float2bfloat16(v);
  }
  __syncthreads();
  const int cl = tid & 63;
  #pragma unroll
  for(int p=0; p<16; p++){
    int s_local = p*4 + g4;
    mem_t[((size_t)(b*HW + s0 + s_local))*256 + c0t + cl] = tile[s_local][cl];
  }
}

// ---------- conv weight repack into A-fragment order ----------
__global__ void k_repack(unsigned short* Wp, vp w, size_t wo, int Cin, int Cout, const int* dflag){
  int f = *dflag;
  int slab = blockIdx.x;
  int tap = slab % 9; int t2 = slab / 9;
  int nch = Cin >> 5; int ch = t2 % nch; int cotile = t2 / nch;
  for(int e=threadIdx.x; e<2048; e+=256){
    int col = e >> 5, ciL = e & 31;
    size_t co = cotile*64 + col, ci = ch*32 + ciL;
    float v = ldf(w, wo + (co*Cin + ci)*9 + tap, f);
    Wp[(size_t)slab*2048 + e] = f2b(v);
  }
}

// ---------- 3x3 conv via MFMA implicit GEMM (repacked weights) ----------
// NCOT cotile groups per block (staging amortized NCOT x). Swizzled LDS.
template<int NCOT>
__global__ __launch_bounds__(256) void k_conv3x3_mfma(
    float* __restrict__ out, const float* __restrict__ in1, const float* __restrict__ in2,
    const unsigned short* __restrict__ Wp, int Cin1, int Cin2, int Cout, int relu,
    vp posp, const int* dflag)
{
  __shared__ __attribute__((aligned(16))) unsigned short Xs[3*66*64];
  const int tid  = threadIdx.x;
  const int lane = tid & 63;
  const int wv   = tid >> 6;
  const int quad = lane >> 4;
  const int l16  = lane & 15;
  const int h    = blockIdx.x;
  const int cotile0 = blockIdx.y * NCOT;
  const int b    = blockIdx.z;
  const int Cin  = Cin1 + Cin2;
  const int nch  = Cin >> 5;
  const int f    = posp ? *dflag : 0;

  if(tid < 96){
    int kh = tid>>5, ci = tid&31;
    int cblk = ci>>3, coff = ci&7;
    Xs[swz(kh*66 + 0,  cblk) + coff] = 0;
    Xs[swz(kh*66 + 65, cblk) + coff] = 0;
  }

  f32x4 acc[NCOT][4];
  #pragma unroll
  for(int g=0; g<NCOT; g++)
    #pragma unroll
    for(int nt=0; nt<4; nt++) acc[g][nt] = (f32x4){0.f,0.f,0.f,0.f};

  const unsigned short* wlane = Wp + ((size_t)cotile0*nch)*9*2048 + (wv*16+l16)*32 + quad*8;
  const size_t wgstep = (size_t)nch*9*2048;

  for(int ch=0; ch<nch; ch++){
    __syncthreads();
    #pragma unroll
    for(int it=0; it<6; it++){
      int t   = it*256 + tid;
      int kh  = t >> 9;
      int rem = t & 511;
      int ci  = rem >> 4;
      int w4  = (rem & 15) << 2;
      int r   = h + kh - 1;
      float4 xv = make_float4(0.f,0.f,0.f,0.f);
      int cg = ch*32 + ci;
      if(r >= 0 && r < HT){
        const float* srcp = (cg < Cin1) ? in1 + ((size_t)(b*Cin1+cg))*HW
                                        : in2 + ((size_t)(b*Cin2+(cg-Cin1)))*HW;
        xv = *(const float4*)(srcp + r*WD + w4);
        if(posp && cg < Cin1){
          float4 pv = ld4(posp, ((size_t)(b*256+cg))*HW + (size_t)r*WD + w4, f);
          xv.x += pv.x; xv.y += pv.y; xv.z += pv.z; xv.w += pv.w;
        }
      }
      int rowb = kh*66 + w4 + 1;
      int cblk = ci>>3, coff = ci&7;
      Xs[swz(rowb+0, cblk) + coff] = f2b(xv.x);
      Xs[swz(rowb+1, cblk) + coff] = f2b(xv.y);
      Xs[swz(rowb+2, cblk) + coff] = f2b(xv.z);
      Xs[swz(rowb+3, cblk) + coff] = f2b(xv.w);
    }
    __syncthreads();
    const unsigned short* wch = wlane + (size_t)ch*9*2048;
    #pragma unroll
    for(int tap=0; tap<9; tap++){
      const int kh = tap/3, kw = tap%3;
      bf16x8 bfr[4];
      #pragma unroll
      for(int nt=0; nt<4; nt++)
        bfr[nt] = *(const bf16x8*)&Xs[swz(kh*66 + nt*16 + l16 + kw, quad)];
      #pragma unroll
      for(int g=0; g<NCOT; g++){
        bf16x8 af = *(const bf16x8*)(wch + (size_t)g*wgstep + tap*2048);
        #pragma unroll
        for(int nt=0; nt<4; nt++)
          acc[g][nt] = __builtin_amdgcn_mfma_f32_16x16x32_bf16(af, bfr[nt], acc[g][nt], 0, 0, 0);
      }
    }
  }
  #pragma unroll
  for(int g=0; g<NCOT; g++){
    #pragma unroll
    for(int nt=0; nt<4; nt++){
      #pragma unroll
      for(int r=0; r<4; r++){
        float vv = acc[g][nt][r];
        if(relu) vv = fmaxf(vv, 0.f);
        out[((size_t)(b*Cout + (cotile0+g)*64 + wv*16 + quad*4 + r))*HW + h*WD + nt*16 + l16] = vv;
      }
    }
  }
}

// ---------- MFMA GEMM with bf16 output ----------
__global__ __launch_bounds__(256) void k_gemm_mfma(
    __hip_bfloat16* __restrict__ Y, const float* __restrict__ X, vp W, size_t wo,
    vp bias, size_t bo, vp pos2, int M, int N, int K, const int* dflag)
{
  __shared__ __attribute__((aligned(16))) unsigned short Xs[64*40];
  __shared__ __attribute__((aligned(16))) unsigned short Ws[64*40];
  if(blockIdx.z){ wo += 65536; bo += 256; pos2 = nullptr; Y += 16777216; }
  const int f = *dflag;
  const int tid = threadIdx.x;
  const int bn = blockIdx.x*64, bm = blockIdx.y*64;
  const int lane = tid & 63, wv = tid >> 6, quad = lane >> 4, l16 = lane & 15;
  const int row = tid >> 2, kq = (tid & 3) * 8;

  f32x4 acc[4];
  #pragma unroll
  for(int mt=0; mt<4; mt++) acc[mt] = (f32x4){0.f,0.f,0.f,0.f};

  for(int k0=0; k0<K; k0+=32){
    __syncthreads();
    {
      int gm = bm + row;
      const float* xp = X + (size_t)gm*K + k0 + kq;
      float4 xa = *(const float4*)xp;
      float4 xb = *(const float4*)(xp+4);
      if(pos2){
        int b = gm >> 12, s = gm & 4095;
        size_t pb = ((size_t)(b*256 + k0 + kq))*HW + s;
        xa.x += ldf(pos2, pb,      f); xa.y += ldf(pos2, pb+HW,   f);
        xa.z += ldf(pos2, pb+2*HW, f); xa.w += ldf(pos2, pb+3*HW, f);
        xb.x += ldf(pos2, pb+4*HW, f); xb.y += ldf(pos2, pb+5*HW, f);
        xb.z += ldf(pos2, pb+6*HW, f); xb.w += ldf(pos2, pb+7*HW, f);
      }
      ushort8 xo;
      xo[0]=f2b(xa.x); xo[1]=f2b(xa.y); xo[2]=f2b(xa.z); xo[3]=f2b(xa.w);
      xo[4]=f2b(xb.x); xo[5]=f2b(xb.y); xo[6]=f2b(xb.z); xo[7]=f2b(xb.w);
      *(ushort8*)&Xs[row*40 + kq] = xo;
    }
    {
      size_t wr = wo + (size_t)(bn + row)*K + k0 + kq;
      ushort8 wo8;
      if(f){
        const float* wp2 = (const float*)W + wr;
        float4 wa = *(const float4*)wp2;
        float4 wb = *(const float4*)(wp2+4);
        wo8[0]=f2b(wa.x); wo8[1]=f2b(wa.y); wo8[2]=f2b(wa.z); wo8[3]=f2b(wa.w);
        wo8[4]=f2b(wb.x); wo8[5]=f2b(wb.y); wo8[6]=f2b(wb.z); wo8[7]=f2b(wb.w);
      } else {
        wo8 = *(const ushort8*)((const unsigned short*)W + wr);
      }
      *(ushort8*)&Ws[row*40 + kq] = wo8;
    }
    __syncthreads();
    bf16x8 bfr = *(const bf16x8*)&Ws[(wv*16 + l16)*40 + quad*8];
    #pragma unroll
    for(int mt=0; mt<4; mt++){
      bf16x8 af = *(const bf16x8*)&Xs[(mt*16 + l16)*40 + quad*8];
      acc[mt] = __builtin_amdgcn_mfma_f32_16x16x32_bf16(af, bfr, acc[mt], 0, 0, 0);
    }
  }
  const int n = bn + wv*16 + l16;
  const float bv = ldf(bias, bo + n, f);
  #pragma unroll
  for(int mt=0; mt<4; mt++){
    #pragma unroll
    for(int r=0; r<4; r++){
      int m = bm + mt*16 + quad*4 + r;
      Y[(size_t)m*N + n] = __float2bfloat16(acc[mt][r] + bv);
    }
  }
}

// ---------- merged 1x1 convs for criss-cross q/k/v (Cin=64) ----------
__global__ __launch_bounds__(64) void k_conv1x1_qkv(
    float* __restrict__ qout, float* __restrict__ kout, float* __restrict__ vout,
    const float* __restrict__ in,
    vp qw, size_t qwo, vp qb, size_t qbo,
    vp kw, size_t kwo, vp kb2, size_t kbo,
    vp vw, size_t vwo, vp vb2, size_t vbo, const int* dflag)
{
  __shared__ float wl[64];
  int f = *dflag;
  int tid = threadIdx.x; int cy = blockIdx.y; int b = blockIdx.z;
  int p = blockIdx.x*64 + tid;

  vp w; size_t wo2; vp bi; size_t bo2; float* out; int co; int oc;
  if(cy < 8)      { w=qw; wo2=qwo; bi=qb;  bo2=qbo; out=qout; co=cy;    oc=8;  }
  else if(cy < 16){ w=kw; wo2=kwo; bi=kb2; bo2=kbo; out=kout; co=cy-8;  oc=8;  }
  else            { w=vw; wo2=vwo; bi=vb2; bo2=vbo; out=vout; co=cy-16; oc=64; }

  wl[tid] = ldf(w, wo2 + (size_t)co*64 + tid, f);
  __syncthreads();
  float acc = ldf(bi, bo2 + co, f);
  for(int c=0; c<64; c++) acc += in[((size_t)(b*64+c))*HW + p]*wl[c];
  out[((size_t)(b*oc+co))*HW + p] = acc;
}

// ---------- fused criss-cross: energies + softmax + aggregation ----------
__global__ __launch_bounds__(256) void k_cc_fused(
    float* __restrict__ out, const float* __restrict__ v,
    const float* __restrict__ q, const float* __restrict__ k,
    const float* __restrict__ x, vp gamma, size_t go, const int* dflag)
{
  __shared__ float E[64*129];
  __shared__ float Vh[64*65];
  __shared__ float qs[8*64];
  __shared__ float kh[8*64];
  __shared__ float red[4*64];
  __shared__ float Mw[64], Sw[64];
  const int tid = threadIdx.x, lane = tid & 63, wv = tid >> 6;
  const int h = blockIdx.x, b = blockIdx.y;
  const int f = *dflag;

  for(int cc=wv; cc<8; cc+=4){
    qs[cc*64+lane] = q[((size_t)(b*8+cc))*HW + h*WD + lane];
    kh[cc*64+lane] = k[((size_t)(b*8+cc))*HW + h*WD + lane];
  }
  for(int cc=wv; cc<64; cc+=4)
    Vh[cc*65+lane] = v[((size_t)(b*64+cc))*HW + h*WD + lane];
  __syncthreads();

  {
    const int w = lane;
    for(int jt=0; jt<32; jt++){
      int j = wv*32 + jt;
      float e = 0.f;
      if(j < 64){
        const float* kcol = k + ((size_t)(b*8))*HW + (size_t)j*WD + w;
        #pragma unroll
        for(int c=0;c<8;c++) e += qs[c*64+w]*kcol[(size_t)c*HW];
        if(j == h) e += NEGV;
      } else {
        int jj = j - 64;
        #pragma unroll
        for(int c=0;c<8;c++) e += qs[c*64+w]*kh[c*64+jj];
      }
      E[w*129 + j] = e;
    }
  }
  __syncthreads();
  {
    const int w = lane;
    float mx = -1e30f;
    for(int jt=0; jt<32; jt++) mx = fmaxf(mx, E[w*129 + wv*32 + jt]);
    red[wv*64+w] = mx;
  }
  __syncthreads();
  if(wv==0){
    int w = lane;
    Mw[w] = fmaxf(fmaxf(red[w], red[64+w]), fmaxf(red[128+w], red[192+w]));
  }
  __syncthreads();
  {
    const int w = lane;
    float mx = Mw[w], s = 0.f;
    for(int jt=0; jt<32; jt++){
      int j = wv*32 + jt;
      float p = __expf(E[w*129+j] - mx);
      E[w*129+j] = p;
      s += p;
    }
    red[wv*64+w] = s;
  }
  __syncthreads();
  if(wv==0){
    int w = lane;
    Sw[w] = 1.0f/(red[w]+red[64+w]+red[128+w]+red[192+w]);
  }
  __syncthreads();
  {
    const int w = lane;
    const int c0 = wv*16;
    float acc[16];
    #pragma unroll
    for(int i=0;i<16;i++) acc[i] = 0.f;
    const float* vbase = v + ((size_t)(b*64 + c0))*HW + w;
    for(int j=0;j<64;j++){
      float p = E[w*129 + j];
      const float* vcol = vbase + (size_t)j*WD;
      #pragma unroll
      for(int i=0;i<16;i++) acc[i] += vcol[(size_t)i*HW]*p;
    }
    for(int j=0;j<64;j++){
      float p = E[w*129 + 64 + j];
      #pragma unroll
      for(int i=0;i<16;i++) acc[i] += Vh[(c0+i)*65 + j]*p;
    }
    float g = ldf(gamma, go, f);
    float inv = Sw[w];
    #pragma unroll
    for(int i=0;i<16;i++){
      size_t idx = ((size_t)(b*64 + c0 + i))*HW + (size_t)h*WD + w;
      out[idx] = g*(acc[i]*inv) + x[idx];
    }
  }
}

// ---------- fp32 GEMM (small M) ----------
__global__ __launch_bounds__(256) void k_gemm(
    float* __restrict__ Y, const float* __restrict__ X, vp W, size_t wo,
    vp bias, size_t bo, vp qe, int M, int N, int Kstride, int kchunk,
    int mode, int relu, const int* dflag)
{
  __shared__ float Xs[16][68];
  __shared__ float Ws[16][68];
  int f = *dflag;
  int tid = threadIdx.x;
  int bn = blockIdx.x*64, bm = blockIdx.y*64;
  int z = blockIdx.z;
  int k0base = 0, dobias = 1;
  if(mode == 1){
    wo += (size_t)z*65536; bo += (size_t)z*256; Y += (size_t)z*102400;
    if(z == 2) qe = nullptr;
  } else if(mode == 2){
    k0base = z*kchunk; Y += (size_t)z*102400; dobias = (z == 0);
  }
  int tx = tid & 15, ty = tid >> 4;
  int mload = tid >> 2;
  int k4 = (tid & 3) * 4;
  float acc[4][4] = {{0}};
  for(int k0=0; k0<kchunk; k0+=16){
    float4 xv = make_float4(0.f,0.f,0.f,0.f);
    int gm = bm + mload;
    if(gm < M){
      xv = *(const float4*)(X + (size_t)gm*Kstride + k0base + k0 + k4);
      if(qe){
        float4 pv = ld4(qe, (size_t)(gm>>2)*256 + k0base + k0 + k4, f);
        xv.x += pv.x; xv.y += pv.y; xv.z += pv.z; xv.w += pv.w;
      }
    }
    Xs[k4+0][mload] = xv.x; Xs[k4+1][mload] = xv.y;
    Xs[k4+2][mload] = xv.z; Xs[k4+3][mload] = xv.w;
    size_t wr = wo + (size_t)(bn + mload)*Kstride + k0base + k0 + k4;
    Ws[k4+0][mload] = ldf(W, wr,   f); Ws[k4+1][mload] = ldf(W, wr+1, f);
    Ws[k4+2][mload] = ldf(W, wr+2, f); Ws[k4+3][mload] = ldf(W, wr+3, f);
    __syncthreads();
    #pragma unroll
    for(int kk=0; kk<16; kk++){
      float a0=Xs[kk][ty*4+0], a1=Xs[kk][ty*4+1], a2=Xs[kk][ty*4+2], a3=Xs[kk][ty*4+3];
      float b0=Ws[kk][tx*4+0], b1=Ws[kk][tx*4+1], b2=Ws[kk][tx*4+2], b3=Ws[kk][tx*4+3];
      acc[0][0]+=a0*b0; acc[0][1]+=a0*b1; acc[0][2]+=a0*b2; acc[0][3]+=a0*b3;
      acc[1][0]+=a1*b0; acc[1][1]+=a1*b1; acc[1][2]+=a1*b2; acc[1][3]+=a1*b3;
      acc[2][0]+=a2*b0; acc[2][1]+=a2*b1; acc[2][2]+=a2*b2; acc[2][3]+=a2*b3;
      acc[3][0]+=a3*b0; acc[3][1]+=a3*b1; acc[3][2]+=a3*b2; acc[3][3]+=a3*b3;
    }
    __syncthreads();
  }
  #pragma unroll
  for(int i=0;i<4;i++){
    int m = bm + ty*4 + i;
    if(m >= M) continue;
    #pragma unroll
    for(int j=0;j<4;j++){
      int n = bn + tx*4 + j;
      float vv = acc[i][j] + ((dobias && bias) ? ldf(bias, bo + n, f) : 0.f);
      if(relu) vv = fmaxf(vv, 0.f);
      Y[(size_t)m*N + n] = vv;
    }
  }
}

// ---------- self-attention (fp32 K/V, small S) ----------
__global__ __launch_bounds__(64) void k_attn(
    float* __restrict__ out, const float* __restrict__ q,
    const float* __restrict__ k, const float* __restrict__ v,
    int B, int S, size_t bstride, size_t sstride, float scale)
{
  int lane = threadIdx.x;
  int l = blockIdx.x, h = blockIdx.y, b = blockIdx.z;
  const float4* qp = (const float4*)(q + ((size_t)(l*B+b))*256 + h*32);
  float4 qr[8];
  #pragma unroll
  for(int d=0; d<8; d++) qr[d] = qp[d];
  float m = -1e30f, lsum = 0.f;
  float acc[32];
  #pragma unroll
  for(int d=0; d<32; d++) acc[d] = 0.f;
  for(int s=lane; s<S; s+=64){
    const float4* kp = (const float4*)(k + b*bstride + (size_t)s*sstride + h*32);
    const float4* vp2 = (const float4*)(v + b*bstride + (size_t)s*sstride + h*32);
    float e = 0.f;
    #pragma unroll
    for(int d=0; d<8; d++){
      float4 kv = kp[d];
      e += qr[d].x*kv.x + qr[d].y*kv.y + qr[d].z*kv.z + qr[d].w*kv.w;
    }
    e *= scale;
    float nm = fmaxf(m, e);
    float ff = __expf(m - nm);
    float p = __expf(e - nm);
    lsum = lsum*ff + p;
    #pragma unroll
    for(int d=0; d<8; d++){
      float4 vv = vp2[d];
      acc[4*d+0] = acc[4*d+0]*ff + p*vv.x;
      acc[4*d+1] = acc[4*d+1]*ff + p*vv.y;
      acc[4*d+2] = acc[4*d+2]*ff + p*vv.z;
      acc[4*d+3] = acc[4*d+3]*ff + p*vv.w;
    }
    m = nm;
  }
  #pragma unroll
  for(int off=32; off>0; off>>=1){
    float om = __shfl_xor(m, off);
    float ol = __shfl_xor(lsum, off);
    float nm = fmaxf(m, om);
    float fa = __expf(m - nm), fb = __expf(om - nm);
    lsum = lsum*fa + ol*fb;
    #pragma unroll
    for(int d=0; d<32; d++){
      float oa = __shfl_xor(acc[d], off);
      acc[d] = acc[d]*fa + oa*fb;
    }
    m = nm;
  }
  if(lane == 0){
    float inv = 1.0f/lsum;
    float* op = out + ((size_t)(l*B+b))*256 + h*32;
    #pragma unroll
    for(int d=0; d<32; d++) op[d] = acc[d]*inv;
  }
}

// ---------- cross-attention via MFMA flash ----------
__global__ __launch_bounds__(256) void k_attn_x(
    float* __restrict__ part, const float* __restrict__ q,
    const __hip_bfloat16* __restrict__ k, const __hip_bfloat16* __restrict__ v,
    float scale)
{
  __shared__ float Om[4][16][33];
  __shared__ float Mm[4][16], Ll[4][16];
  const int tid = threadIdx.x, lane = tid & 63, wv = tid >> 6;
  const int quad = lane >> 4, l16 = lane & 15;
  const int qtile = blockIdx.x, h = blockIdx.y;
  const int b = blockIdx.z >> 2, chunk = blockIdx.z & 3;

  int l = qtile*16 + l16; if(l > 99) l = 99;
  const float* qp = q + ((size_t)(l*4 + b))*256 + h*32 + quad*8;
  union { ushort8 u; bf16x8 b; } qf;
  #pragma unroll
  for(int j=0;j<8;j++) qf.u[j] = f2b(qp[j]);

  const unsigned short* kb = (const unsigned short*)k + ((size_t)b*HW)*256 + h*32;
  const unsigned short* vb = (const unsigned short*)v + ((size_t)b*HW)*256 + h*32;

  float m = -1e30f, ls = 0.f;
  f32x4 oA = (f32x4){0.f,0.f,0.f,0.f};
  f32x4 oB = (f32x4){0.f,0.f,0.f,0.f};

  const int kb0 = chunk*1024 + wv*256;
  for(int it=0; it<4; it++){
    const int kbase = kb0 + it*64;
    f32x4 st[4];
    #pragma unroll
    for(int t=0;t<4;t++){
      union { ushort8 u; bf16x8 b; } kf;
      kf.u = *(const ushort8*)(kb + (size_t)(kbase + t*16 + l16)*256 + quad*8);
      st[t] = __builtin_amdgcn_mfma_f32_16x16x32_bf16(kf.b, qf.b,
              (f32x4){0.f,0.f,0.f,0.f}, 0, 0, 0);
    }
    float mx = -1e30f;
    #pragma unroll
    for(int t=0;t<4;t++){
      #pragma unroll
      for(int r=0;r<4;r++){ st[t][r] *= scale; mx = fmaxf(mx, st[t][r]); }
    }
    mx = fmaxf(mx, __shfl_xor(mx, 16));
    mx = fmaxf(mx, __shfl_xor(mx, 32));
    float nm = fmaxf(m, mx);
    float ff = __expf(m - nm);
    m = nm;
    ls *= ff;
    #pragma unroll
    for(int r=0;r<4;r++){
      float fr = __shfl(ff, quad*4 + r);
      oA[r] *= fr; oB[r] *= fr;
    }
    unsigned int pk[4][2];
    #pragma unroll
    for(int t=0;t<4;t++){
      float p0 = __expf(st[t][0]-m), p1 = __expf(st[t][1]-m);
      float p2 = __expf(st[t][2]-m), p3 = __expf(st[t][3]-m);
      ls += (p0+p1) + (p2+p3);
      pk[t][0] = (unsigned int)f2b(p0) | ((unsigned int)f2b(p1)<<16);
      pk[t][1] = (unsigned int)f2b(p2) | ((unsigned int)f2b(p3)<<16);
    }
    #pragma unroll
    for(int m2=0;m2<2;m2++){
      union { int w[4]; bf16x8 b; } pa;
      const int srcl = ((quad&1)*2)*16 + l16;
      #pragma unroll
      for(int w=0;w<4;w++){
        int sl = srcl + ((w>>1)<<4);
        int wa = __shfl((int)pk[m2*2  ][w&1], sl);
        int wb = __shfl((int)pk[m2*2+1][w&1], sl);
        pa.w[w] = (quad < 2) ? wa : wb;
      }
      const unsigned short* vrow = vb + (size_t)(kbase + m2*32 + quad*8)*256 + l16;
      union { ushort8 u; bf16x8 b; } va, vc;
      #pragma unroll
      for(int j=0;j<8;j++){
        va.u[j] = vrow[(size_t)j*256];
        vc.u[j] = vrow[(size_t)j*256 + 16];
      }
      oA = __builtin_amdgcn_mfma_f32_16x16x32_bf16(pa.b, va.b, oA, 0, 0, 0);
      oB = __builtin_amdgcn_mfma_f32_16x16x32_bf16(pa.b, vc.b, oB, 0, 0, 0);
    }
  }
  ls += __shfl_xor(ls, 16);
  ls += __shfl_xor(ls, 32);
  #pragma unroll
  for(int r=0;r<4;r++){
    Om[wv][quad*4+r][l16]    = oA[r];
    Om[wv][quad*4+r][16+l16] = oB[r];
  }
  if(lane < 16){ Mm[wv][lane] = m; Ll[wv][lane] = ls; }
  __syncthreads();
  if(wv == 0){
    const int qq = lane >> 2;
    float M = fmaxf(fmaxf(Mm[0][qq], Mm[1][qq]), fmaxf(Mm[2][qq], Mm[3][qq]));
    float f0 = __expf(Mm[0][qq]-M), f1 = __expf(Mm[1][qq]-M);
    float f2 = __expf(Mm[2][qq]-M), f3 = __expf(Mm[3][qq]-M);
    int lq = qtile*16 + qq;
    if(lq <= 99){
      float* pr = part + ((size_t)(((chunk*100 + lq)*8 + h)*4 + b))*36;
      #pragma unroll
      for(int i=0;i<8;i++){
        int dh = ((lane&3)<<3) + i;
        float O = Om[0][qq][dh]*f0 + Om[1][qq][dh]*f1
                + Om[2][qq][dh]*f2 + Om[3][qq][dh]*f3;
        pr[dh] = O;
      }
      if((lane & 3) == 0){
        float L = Ll[0][qq]*f0 + Ll[1][qq]*f1 + Ll[2][qq]*f2 + Ll[3][qq]*f3;
        pr[32] = M; pr[33] = L;
      }
    }
  }
}

// ---------- merge 4 S-chunk partials -> attout ----------
__global__ __launch_bounds__(256) void k_attn_xmrg(
    float* __restrict__ out, const float* __restrict__ part)
{
  const int l = blockIdx.x, tid = threadIdx.x;
  const int b = tid >> 6, h = (tid >> 3) & 7, dl = tid & 7;
  const float* p0 = part + ((size_t)(((0*100 + l)*8 + h)*4 + b))*36;
  float M = p0[32], L = p0[33];
  float4 A = *(const float4*)(p0 + dl*4);
  #pragma unroll
  for(int c=1; c<4; c++){
    const float* pc = part + ((size_t)(((c*100 + l)*8 + h)*4 + b))*36;
    float om = pc[32], ol = pc[33];
    float4 oa = *(const float4*)(pc + dl*4);
    float nm = fmaxf(M, om);
    float fa = __expf(M - nm), fb = __expf(om - nm);
    L = L*fa + ol*fb;
    A.x = A.x*fa + oa.x*fb; A.y = A.y*fa + oa.y*fb;
    A.z = A.z*fa + oa.z*fb; A.w = A.w*fa + oa.w*fb;
    M = nm;
  }
  float inv = 1.0f/L;
  *(float4*)(out + ((size_t)(l*4 + b))*256 + h*32 + dl*4) =
      make_float4(A.x*inv, A.y*inv, A.z*inv, A.w*inv);
}

// ---------- LayerNorm over C=256 ----------
__global__ __launch_bounds__(256) void k_ln(
    float* dst, const float* x, const float* t2, int nsl,
    vp g, vp bb, size_t go, const int* dflag)
{
  __shared__ float red[256];
  int f = *dflag;
  int c = threadIdx.x; int tok = blockIdx.x;
  float v = x[(size_t)tok*256 + c];
  if(t2){
    for(int s2=0; s2<nsl; s2++) v += t2[(size_t)s2*102400 + (size_t)tok*256 + c];
  }
  red[c] = v; __syncthreads();
  for(int s=128; s>0; s>>=1){ if(c<s) red[c] += red[c+s]; __syncthreads(); }
  float mu = red[0]*(1.f/256.f);
  __syncthreads();
  float dv = v - mu;
  red[c] = dv*dv; __syncthreads();
  for(int s=128; s>0; s>>=1){ if(c<s) red[c] += red[c+s]; __syncthreads(); }
  float var = red[0]*(1.f/256.f);
  float r = rsqrtf(var + 1e-5f);
  dst[(size_t)tok*256 + c] = dv*r*ldf(g, go+c, f) + ldf(bb, go+c, f);
}

__global__ void k_write_hs(void* out, const float* lnout, const int* dflag){
  int f = *dflag;
  int c = threadIdx.x; int tok = blockIdx.x; int l = tok >> 2; int b = tok & 3;
  float v = lnout[(size_t)tok*256 + c];
  size_t o = ((size_t)(b*100+l))*256 + c;
  if(f) ((float*)out)[o] = v;
  else  ((__hip_bfloat16*)out)[o] = __float2bfloat16(v);
}

extern "C" void kernel_launch(void* const* d_in, const int* in_sizes, int n_in,
                              void* d_out, int out_size, void* d_ws, size_t ws_size,
                              hipStream_t stream) {
  vp src       = d_in[0];
  vp query_emb = d_in[2];
  vp pos       = d_in[3];
  vp conva_w   = d_in[4];
  vp q_w = d_in[5];  vp q_b = d_in[6];
  vp k_w = d_in[7];  vp k_b = d_in[8];
  vp v_w = d_in[9];  vp v_b = d_in[10];
  vp gamma = d_in[11];
  vp convb_w = d_in[12];
  vp bneck_w = d_in[13];
  vp sa_in_w = d_in[14];  vp sa_in_b = d_in[15];
  vp sa_out_w = d_in[16]; vp sa_out_b = d_in[17];
  vp ca_in_w = d_in[18];  vp ca_in_b = d_in[19];
  vp ca_out_w = d_in[20]; vp ca_out_b = d_in[21];
  vp lin1_w = d_in[22];   vp lin1_b = d_in[23];
  vp lin2_w = d_in[24];   vp lin2_b = d_in[25];
  vp n1g = d_in[26]; vp n1b = d_in[27];
  vp n2g = d_in[28]; vp n2b = d_in[29];
  vp n3g = d_in[30]; vp n3b = d_in[31];
  vp normg = d_in[32]; vp normb = d_in[33];

  const size_t MEG = 1048576;
  float* ws   = (float*)d_ws;
  float* memf  = ws;                    // 4M floats (ping)
  float* xi    = ws + 4*MEG;            // 4M (pong; later mem_t)
  float* y64a  = ws + 8*MEG;            // 1M
  float* y64b  = ws + 9*MEG;            // 1M
  float* vb_   = ws + 10*MEG;           // 1M
  float* qb_   = ws + 11*MEG;           // 128K
  float* kb_   = ws + 11*MEG + 131072;  // 128K
  float* y256  = ws + 9*MEG;            // 4M (overlaps dead cc buffers)
  float* mem_t = xi;                    // decoder tokens
  __hip_bfloat16* kproj = (__hip_bfloat16*)memf;            // 16384x256 bf16
  __hip_bfloat16* vproj = (__hip_bfloat16*)(ws + 8*MEG);    // == kproj + 16777216 elems
  float* psum  = ws + 10*MEG;           // 819200 floats (K-split partials / attn_x partials)
  float* sm    = ws + 13*MEG + 262144;
  float* outq   = sm;
  float* qproj  = sm + 204800;
  float* kself  = sm + 307200;
  float* vself  = sm + 409600;
  float* attout = sm + 512000;
  float* t2     = sm + 614400;
  float* ffn1   = sm + 716800;
  float* lnout  = sm + 1536000;
  unsigned short* Wp = (unsigned short*)(ws + 15532032);
  int*   dflag  = (int*)(ws + 15532032 + 589824);

  const int NFULL = 4194304;
  const float scale = 0.17677669529663687f;

  k_detect<<<1, 256, 0, stream>>>(dflag, (const unsigned short*)src);
  k_cvt<<<4096, 256, 0, stream>>>((float4*)memf, src, NFULL/4, dflag);

  // ------------- encoder (mem ping-pongs memf<->xi; pos fused into conv staging) -------------
  float* cur = memf;
  float* nxt = xi;
  for(int i=0; i<6; i++){
    k_repack<<<72, 256, 0, stream>>>(Wp, conva_w, (size_t)i*147456, 256, 64, dflag);
    k_conv3x3_mfma<1><<<dim3(64,1,4), 256, 0, stream>>>(y64a, cur, nullptr, Wp, 256, 0, 64, 1, pos, dflag);
    for(int pass=0; pass<2; pass++){
      const float* cx = pass ? y64b : y64a;
      float* cy       = pass ? y64a : y64b;
      k_conv1x1_qkv<<<dim3(64,80,4), 64, 0, stream>>>(qb_, kb_, vb_, cx,
          q_w, (size_t)i*512,  q_b, (size_t)i*8,
          k_w, (size_t)i*512,  k_b, (size_t)i*8,
          v_w, (size_t)i*4096, v_b, (size_t)i*64, dflag);
      k_cc_fused<<<dim3(64,4), 256, 0, stream>>>(cy, vb_, qb_, kb_, cx, gamma, (size_t)i, dflag);
    }
    k_repack<<<72, 256, 0, stream>>>(Wp, convb_w, (size_t)i*147456, 64, 256, dflag);
    k_conv3x3_mfma<2><<<dim3(64,2,4), 256, 0, stream>>>(y256, y64a, nullptr, Wp, 64, 0, 256, 1, nullptr, dflag);
    k_repack<<<576, 256, 0, stream>>>(Wp, bneck_w, (size_t)i*1179648, 512, 256, dflag);
    k_conv3x3_mfma<2><<<dim3(64,2,4), 256, 0, stream>>>(nxt, cur, y256, Wp, 256, 256, 256, 0, pos, dflag);
    float* tmp = cur; cur = nxt; nxt = tmp;
  }
  // 6 layers (even) -> cur == memf here.

  // ------------- decoder prep: fused transpose + memory_2d write (before kproj overwrites memf) -------------
  k_finalize_mem<<<dim3(64,4,4), 256, 0, stream>>>(mem_t, d_out, cur, dflag);
  k_zero<<<400, 256, 0, stream>>>(outq, 102400);

  // ------------- decoder layers -------------
  for(int i=0; i<6; i++){
    size_t iw = (size_t)i*196608, ib = (size_t)i*768;
    size_t ow = (size_t)i*65536,  ob = (size_t)i*256;
    // self-attention: batched q/k/v projections (qe fused for q,k; not v)
    k_gemm<<<dim3(4,7,3), 256, 0, stream>>>(qproj, outq, sa_in_w, iw, sa_in_b, ib, query_emb, 400, 256, 256, 256, 1, 0, dflag);
    k_attn<<<dim3(100,8,4), 64, 0, stream>>>(attout, qproj, kself, vself,
        4, 100, (size_t)256, (size_t)1024, scale);
    // out-proj: 4-way K-split into psum, reduced in k_ln
    k_gemm<<<dim3(4,7,4), 256, 0, stream>>>(psum, attout, sa_out_w, ow, sa_out_b, ob, nullptr, 400, 256, 256, 64, 2, 0, dflag);
    k_ln<<<400, 256, 0, stream>>>(outq, outq, psum, 4, n1g, n1b, ob, dflag);
    // cross-attention: qe fused into qproj; k/v MFMA projections batched (z=2)
    k_gemm<<<dim3(4,7), 256, 0, stream>>>(qproj, outq, ca_in_w, iw, ca_in_b, ib, query_emb, 400, 256, 256, 256, 0, 0, dflag);
    k_gemm_mfma<<<dim3(4,256,2), 256, 0, stream>>>(kproj, mem_t, ca_in_w, iw+65536, ca_in_b, ib+256, pos, 16384, 256, 256, dflag);
    // MFMA flash cross-attention: partials into psum, then merge
    k_attn_x<<<dim3(7,8,16), 256, 0, stream>>>(psum, qproj, kproj, vproj, scale);
    k_attn_xmrg<<<100, 256, 0, stream>>>(attout, psum);
    k_gemm<<<dim3(4,7,4), 256, 0, stream>>>(psum, attout, ca_out_w, ow, ca_out_b, ob, nullptr, 400, 256, 256, 64, 2, 0, dflag);
    k_ln<<<400, 256, 0, stream>>>(outq, outq, psum, 4, n2g, n2b, ob, dflag);
    // FFN: ffn1 plain; ffn2 8-way K-split, reduced inside k_ln
    k_gemm<<<dim3(32,7), 256, 0, stream>>>(ffn1, outq, lin1_w, (size_t)i*524288, lin1_b, (size_t)i*2048, nullptr, 400, 2048, 256, 256, 0, 1, dflag);
    k_gemm<<<dim3(4,7,8), 256, 0, stream>>>(psum, ffn1, lin2_w, (size_t)i*524288, lin2_b, ob, nullptr, 400, 256, 2048, 256, 2, 0, dflag);
    k_ln<<<400, 256, 0, stream>>>(outq, outq, psum, 8, n3g, n3b, ob, dflag);
  }

  k_ln<<<400, 256, 0, stream>>>(lnout, outq, nullptr, 0, normg, normb, (size_t)0, dflag);
  k_write_hs<<<400, 256, 0, stream>>>(d_out, lnout, dflag);
}

// Round 11
// 3107.709 us; speedup vs baseline: 1.0561x; 1.0561x over previous
//
#include <hip/hip_runtime.h>
#include <hip/hip_bf16.h>

#define HW 4096
#define WD 64
#define HT 64
#define NEGV -1000000000.0f

typedef const void* vp;
typedef __attribute__((ext_vector_type(8))) short bf16x8;
typedef __attribute__((ext_vector_type(8))) unsigned short ushort8;
typedef __attribute__((ext_vector_type(4))) float f32x4;

__device__ __forceinline__ float b2f(__hip_bfloat16 v){ return __bfloat162float(v); }
__device__ __forceinline__ float ldf(vp p, size_t i, int f){
  return f ? ((const float*)p)[i] : b2f(((const __hip_bfloat16*)p)[i]);
}
__device__ __forceinline__ unsigned short f2b(float x){
  __hip_bfloat16 h = __float2bfloat16(x);
  return *reinterpret_cast<unsigned short*>(&h);
}
__device__ __forceinline__ float u2f(unsigned short u){
  union { unsigned int i; float f; } x; x.i = ((unsigned int)u) << 16; return x.f;
}
__device__ __forceinline__ float4 ld4(vp p, size_t i, int f){
  if(f) return *(const float4*)((const float*)p + i);
  ushort4 u = *(const ushort4*)((const unsigned short*)p + i);
  return make_float4(u2f(u.x), u2f(u.y), u2f(u.z), u2f(u.w));
}

// LDS conv-tile swizzle: 64-ushort rows (8x16B blocks), block XOR keyed on
// (row ^ row>>3)&7.
__device__ __forceinline__ int swz(int row, int blk){
  return row*64 + (((blk ^ ((row ^ (row>>3)) & 7)) << 3));
}

// ---------- dtype detector ----------
__global__ void k_detect(int* flag, const unsigned short* p){
  __shared__ int cnt;
  if(threadIdx.x==0) cnt=0;
  __syncthreads();
  int c=0;
  for(int i=threadIdx.x; i<512; i+=256){
    int e = (p[i]>>7)&0xFF;
    if(e>150 || e<100) c++;
  }
  atomicAdd(&cnt, c);
  __syncthreads();
  if(threadIdx.x==0) *flag = (cnt>32) ? 1 : 0;  // 1 = fp32 inputs
}

// ---------- elementwise (vectorized x4) ----------
__global__ void k_cvt(float4* dst, vp src, int n4, const int* dflag){
  int f = *dflag;
  int i = blockIdx.x*256 + threadIdx.x;
  if(i<n4) dst[i] = ld4(src, (size_t)i*4, f);
}

__global__ void k_zero(float* p, int n){
  int i = blockIdx.x*256 + threadIdx.x;
  if(i<n) p[i] = 0.f;
}

// ---------- fused token transpose + memory_2d output write ----------
__global__ __launch_bounds__(256) void k_finalize_mem(
    float* __restrict__ mem_t, void* __restrict__ dout,
    const float* __restrict__ memf, const int* dflag)
{
  __shared__ float tile[64][65];
  const int f = *dflag;
  const int tid = threadIdx.x;
  const int s0 = blockIdx.x*64, c0t = blockIdx.y*64, b = blockIdx.z;
  const int sl = tid & 63, g4 = tid >> 6;
  #pragma unroll
  for(int p=0; p<16; p++){
    int cl = p*4 + g4;
    float v = memf[((size_t)(b*256 + c0t + cl))*HW + s0 + sl];
    tile[sl][cl] = v;
    size_t o = 102400 + ((size_t)(b*256 + c0t + cl))*HW + s0 + sl;
    if(f) ((float*)dout)[o] = v;
    else  ((__hip_bfloat16*)dout)[o] = __float2bfloat16(v);
  }
  __syncthreads();
  const int cl = tid & 63;
  #pragma unroll
  for(int p=0; p<16; p++){
    int s_local = p*4 + g4;
    mem_t[((size_t)(b*HW + s0 + s_local))*256 + c0t + cl] = tile[s_local][cl];
  }
}

// ---------- conv weight repack into A-fragment order ----------
__global__ void k_repack(unsigned short* Wp, vp w, size_t wo, int Cin, int Cout, const int* dflag){
  int f = *dflag;
  int slab = blockIdx.x;
  int tap = slab % 9; int t2 = slab / 9;
  int nch = Cin >> 5; int ch = t2 % nch; int cotile = t2 / nch;
  for(int e=threadIdx.x; e<2048; e+=256){
    int col = e >> 5, ciL = e & 31;
    size_t co = cotile*64 + col, ci = ch*32 + ciL;
    float v = ldf(w, wo + (co*Cin + ci)*9 + tap, f);
    Wp[(size_t)slab*2048 + e] = f2b(v);
  }
}

// ---------- 3x3 conv via MFMA implicit GEMM (repacked weights) ----------
// Swizzled LDS + register-prefetch pipelining: loads for ch+1 are issued
// after barrier B so they overlap the MFMA phase (hipcc drains vmcnt(0) at
// each __syncthreads, so loads issued before a barrier cannot be hidden).
__global__ __launch_bounds__(256) void k_conv3x3_mfma(
    float* __restrict__ out, const float* __restrict__ in1, const float* __restrict__ in2,
    const unsigned short* __restrict__ Wp, int Cin1, int Cin2, int Cout, int relu,
    vp posp, const int* dflag)
{
  __shared__ __attribute__((aligned(16))) unsigned short Xs[3*66*64];
  const int tid  = threadIdx.x;
  const int lane = tid & 63;
  const int wv   = tid >> 6;
  const int quad = lane >> 4;
  const int l16  = lane & 15;
  const int h    = blockIdx.x;
  const int cotile = blockIdx.y;
  const int b    = blockIdx.z;
  const int Cin  = Cin1 + Cin2;
  const int nch  = Cin >> 5;
  const int f    = posp ? *dflag : 0;

  if(tid < 96){
    int kh = tid>>5, ci = tid&31;
    int cblk = ci>>3, coff = ci&7;
    Xs[swz(kh*66 + 0,  cblk) + coff] = 0;
    Xs[swz(kh*66 + 65, cblk) + coff] = 0;
  }

  f32x4 acc[4];
  #pragma unroll
  for(int nt=0; nt<4; nt++) acc[nt] = (f32x4){0.f,0.f,0.f,0.f};

  const unsigned short* wlane = Wp + ((size_t)cotile*nch)*9*2048 + (wv*16+l16)*32 + quad*8;

  float4 xv[6], pv[6];
  auto LOADCH = [&](int ch){
    #pragma unroll
    for(int it=0; it<6; it++){
      int t   = it*256 + tid;
      int kh  = t >> 9;
      int rem = t & 511;
      int ci  = rem >> 4;
      int w4  = (rem & 15) << 2;
      int r   = h + kh - 1;
      xv[it] = make_float4(0.f,0.f,0.f,0.f);
      pv[it] = make_float4(0.f,0.f,0.f,0.f);
      int cg = ch*32 + ci;
      if(r >= 0 && r < HT){
        const float* srcp = (cg < Cin1) ? in1 + ((size_t)(b*Cin1+cg))*HW
                                        : in2 + ((size_t)(b*Cin2+(cg-Cin1)))*HW;
        xv[it] = *(const float4*)(srcp + r*WD + w4);
        if(posp && cg < Cin1)
          pv[it] = ld4(posp, ((size_t)(b*256+cg))*HW + (size_t)r*WD + w4, f);
      }
    }
  };

  LOADCH(0);
  for(int ch=0; ch<nch; ch++){
    __syncthreads();   // barrier A: previous compute done reading Xs
    #pragma unroll
    for(int it=0; it<6; it++){
      int t   = it*256 + tid;
      int kh  = t >> 9;
      int rem = t & 511;
      int ci  = rem >> 4;
      int w4  = (rem & 15) << 2;
      float4 v = xv[it];
      if(posp){ v.x += pv[it].x; v.y += pv[it].y; v.z += pv[it].z; v.w += pv[it].w; }
      int rowb = kh*66 + w4 + 1;
      int cblk = ci>>3, coff = ci&7;
      Xs[swz(rowb+0, cblk) + coff] = f2b(v.x);
      Xs[swz(rowb+1, cblk) + coff] = f2b(v.y);
      Xs[swz(rowb+2, cblk) + coff] = f2b(v.z);
      Xs[swz(rowb+3, cblk) + coff] = f2b(v.w);
    }
    __syncthreads();   // barrier B: Xs ready
    if(ch+1 < nch) LOADCH(ch+1);   // issue next-ch loads; overlap with MFMA below
    const unsigned short* wch = wlane + (size_t)ch*9*2048;
    #pragma unroll
    for(int tap=0; tap<9; tap++){
      const int kh = tap/3, kw = tap%3;
      bf16x8 af = *(const bf16x8*)(wch + tap*2048);
      #pragma unroll
      for(int nt=0; nt<4; nt++){
        bf16x8 bfr = *(const bf16x8*)&Xs[swz(kh*66 + nt*16 + l16 + kw, quad)];
        acc[nt] = __builtin_amdgcn_mfma_f32_16x16x32_bf16(af, bfr, acc[nt], 0, 0, 0);
      }
    }
  }
  #pragma unroll
  for(int nt=0; nt<4; nt++){
    #pragma unroll
    for(int r=0; r<4; r++){
      float vv = acc[nt][r];
      if(relu) vv = fmaxf(vv, 0.f);
      out[((size_t)(b*Cout + cotile*64 + wv*16 + quad*4 + r))*HW + h*WD + nt*16 + l16] = vv;
    }
  }
}

// ---------- MFMA GEMM with bf16 output ----------
__global__ __launch_bounds__(256) void k_gemm_mfma(
    __hip_bfloat16* __restrict__ Y, const float* __restrict__ X, vp W, size_t wo,
    vp bias, size_t bo, vp pos2, int M, int N, int K, const int* dflag)
{
  __shared__ __attribute__((aligned(16))) unsigned short Xs[64*40];
  __shared__ __attribute__((aligned(16))) unsigned short Ws[64*40];
  if(blockIdx.z){ wo += 65536; bo += 256; pos2 = nullptr; Y += 16777216; }
  const int f = *dflag;
  const int tid = threadIdx.x;
  const int bn = blockIdx.x*64, bm = blockIdx.y*64;
  const int lane = tid & 63, wv = tid >> 6, quad = lane >> 4, l16 = lane & 15;
  const int row = tid >> 2, kq = (tid & 3) * 8;

  f32x4 acc[4];
  #pragma unroll
  for(int mt=0; mt<4; mt++) acc[mt] = (f32x4){0.f,0.f,0.f,0.f};

  for(int k0=0; k0<K; k0+=32){
    __syncthreads();
    {
      int gm = bm + row;
      const float* xp = X + (size_t)gm*K + k0 + kq;
      float4 xa = *(const float4*)xp;
      float4 xb = *(const float4*)(xp+4);
      if(pos2){
        int b = gm >> 12, s = gm & 4095;
        size_t pb = ((size_t)(b*256 + k0 + kq))*HW + s;
        xa.x += ldf(pos2, pb,      f); xa.y += ldf(pos2, pb+HW,   f);
        xa.z += ldf(pos2, pb+2*HW, f); xa.w += ldf(pos2, pb+3*HW, f);
        xb.x += ldf(pos2, pb+4*HW, f); xb.y += ldf(pos2, pb+5*HW, f);
        xb.z += ldf(pos2, pb+6*HW, f); xb.w += ldf(pos2, pb+7*HW, f);
      }
      ushort8 xo;
      xo[0]=f2b(xa.x); xo[1]=f2b(xa.y); xo[2]=f2b(xa.z); xo[3]=f2b(xa.w);
      xo[4]=f2b(xb.x); xo[5]=f2b(xb.y); xo[6]=f2b(xb.z); xo[7]=f2b(xb.w);
      *(ushort8*)&Xs[row*40 + kq] = xo;
    }
    {
      size_t wr = wo + (size_t)(bn + row)*K + k0 + kq;
      ushort8 wo8;
      if(f){
        const float* wp2 = (const float*)W + wr;
        float4 wa = *(const float4*)wp2;
        float4 wb = *(const float4*)(wp2+4);
        wo8[0]=f2b(wa.x); wo8[1]=f2b(wa.y); wo8[2]=f2b(wa.z); wo8[3]=f2b(wa.w);
        wo8[4]=f2b(wb.x); wo8[5]=f2b(wb.y); wo8[6]=f2b(wb.z); wo8[7]=f2b(wb.w);
      } else {
        wo8 = *(const ushort8*)((const unsigned short*)W + wr);
      }
      *(ushort8*)&Ws[row*40 + kq] = wo8;
    }
    __syncthreads();
    bf16x8 bfr = *(const bf16x8*)&Ws[(wv*16 + l16)*40 + quad*8];
    #pragma unroll
    for(int mt=0; mt<4; mt++){
      bf16x8 af = *(const bf16x8*)&Xs[(mt*16 + l16)*40 + quad*8];
      acc[mt] = __builtin_amdgcn_mfma_f32_16x16x32_bf16(af, bfr, acc[mt], 0, 0, 0);
    }
  }
  const int n = bn + wv*16 + l16;
  const float bv = ldf(bias, bo + n, f);
  #pragma unroll
  for(int mt=0; mt<4; mt++){
    #pragma unroll
    for(int r=0; r<4; r++){
      int m = bm + mt*16 + quad*4 + r;
      Y[(size_t)m*N + n] = __float2bfloat16(acc[mt][r] + bv);
    }
  }
}

// ---------- merged 1x1 convs for criss-cross q/k/v (Cin=64) ----------
__global__ __launch_bounds__(64) void k_conv1x1_qkv(
    float* __restrict__ qout, float* __restrict__ kout, float* __restrict__ vout,
    const float* __restrict__ in,
    vp qw, size_t qwo, vp qb, size_t qbo,
    vp kw, size_t kwo, vp kb2, size_t kbo,
    vp vw, size_t vwo, vp vb2, size_t vbo, const int* dflag)
{
  __shared__ float wl[64];
  int f = *dflag;
  int tid = threadIdx.x; int cy = blockIdx.y; int b = blockIdx.z;
  int p = blockIdx.x*64 + tid;

  vp w; size_t wo2; vp bi; size_t bo2; float* out; int co; int oc;
  if(cy < 8)      { w=qw; wo2=qwo; bi=qb;  bo2=qbo; out=qout; co=cy;    oc=8;  }
  else if(cy < 16){ w=kw; wo2=kwo; bi=kb2; bo2=kbo; out=kout; co=cy-8;  oc=8;  }
  else            { w=vw; wo2=vwo; bi=vb2; bo2=vbo; out=vout; co=cy-16; oc=64; }

  wl[tid] = ldf(w, wo2 + (size_t)co*64 + tid, f);
  __syncthreads();
  float acc = ldf(bi, bo2 + co, f);
  for(int c=0; c<64; c++) acc += in[((size_t)(b*64+c))*HW + p]*wl[c];
  out[((size_t)(b*oc+co))*HW + p] = acc;
}

// ---------- fused criss-cross: energies + softmax + aggregation ----------
__global__ __launch_bounds__(256) void k_cc_fused(
    float* __restrict__ out, const float* __restrict__ v,
    const float* __restrict__ q, const float* __restrict__ k,
    const float* __restrict__ x, vp gamma, size_t go, const int* dflag)
{
  __shared__ float E[64*129];
  __shared__ float Vh[64*65];
  __shared__ float qs[8*64];
  __shared__ float kh[8*64];
  __shared__ float red[4*64];
  __shared__ float Mw[64], Sw[64];
  const int tid = threadIdx.x, lane = tid & 63, wv = tid >> 6;
  const int h = blockIdx.x, b = blockIdx.y;
  const int f = *dflag;

  for(int cc=wv; cc<8; cc+=4){
    qs[cc*64+lane] = q[((size_t)(b*8+cc))*HW + h*WD + lane];
    kh[cc*64+lane] = k[((size_t)(b*8+cc))*HW + h*WD + lane];
  }
  for(int cc=wv; cc<64; cc+=4)
    Vh[cc*65+lane] = v[((size_t)(b*64+cc))*HW + h*WD + lane];
  __syncthreads();

  {
    const int w = lane;
    for(int jt=0; jt<32; jt++){
      int j = wv*32 + jt;
      float e = 0.f;
      if(j < 64){
        const float* kcol = k + ((size_t)(b*8))*HW + (size_t)j*WD + w;
        #pragma unroll
        for(int c=0;c<8;c++) e += qs[c*64+w]*kcol[(size_t)c*HW];
        if(j == h) e += NEGV;
      } else {
        int jj = j - 64;
        #pragma unroll
        for(int c=0;c<8;c++) e += qs[c*64+w]*kh[c*64+jj];
      }
      E[w*129 + j] = e;
    }
  }
  __syncthreads();
  {
    const int w = lane;
    float mx = -1e30f;
    for(int jt=0; jt<32; jt++) mx = fmaxf(mx, E[w*129 + wv*32 + jt]);
    red[wv*64+w] = mx;
  }
  __syncthreads();
  if(wv==0){
    int w = lane;
    Mw[w] = fmaxf(fmaxf(red[w], red[64+w]), fmaxf(red[128+w], red[192+w]));
  }
  __syncthreads();
  {
    const int w = lane;
    float mx = Mw[w], s = 0.f;
    for(int jt=0; jt<32; jt++){
      int j = wv*32 + jt;
      float p = __expf(E[w*129+j] - mx);
      E[w*129+j] = p;
      s += p;
    }
    red[wv*64+w] = s;
  }
  __syncthreads();
  if(wv==0){
    int w = lane;
    Sw[w] = 1.0f/(red[w]+red[64+w]+red[128+w]+red[192+w]);
  }
  __syncthreads();
  {
    const int w = lane;
    const int c0 = wv*16;
    float acc[16];
    #pragma unroll
    for(int i=0;i<16;i++) acc[i] = 0.f;
    const float* vbase = v + ((size_t)(b*64 + c0))*HW + w;
    for(int j=0;j<64;j++){
      float p = E[w*129 + j];
      const float* vcol = vbase + (size_t)j*WD;
      #pragma unroll
      for(int i=0;i<16;i++) acc[i] += vcol[(size_t)i*HW]*p;
    }
    for(int j=0;j<64;j++){
      float p = E[w*129 + 64 + j];
      #pragma unroll
      for(int i=0;i<16;i++) acc[i] += Vh[(c0+i)*65 + j]*p;
    }
    float g = ldf(gamma, go, f);
    float inv = Sw[w];
    #pragma unroll
    for(int i=0;i<16;i++){
      size_t idx = ((size_t)(b*64 + c0 + i))*HW + (size_t)h*WD + w;
      out[idx] = g*(acc[i]*inv) + x[idx];
    }
  }
}

// ---------- fp32 GEMM (small M) ----------
__global__ __launch_bounds__(256) void k_gemm(
    float* __restrict__ Y, const float* __restrict__ X, vp W, size_t wo,
    vp bias, size_t bo, vp qe, int M, int N, int Kstride, int kchunk,
    int mode, int relu, const int* dflag)
{
  __shared__ float Xs[16][68];
  __shared__ float Ws[16][68];
  int f = *dflag;
  int tid = threadIdx.x;
  int bn = blockIdx.x*64, bm = blockIdx.y*64;
  int z = blockIdx.z;
  int k0base = 0, dobias = 1;
  if(mode == 1){
    wo += (size_t)z*65536; bo += (size_t)z*256; Y += (size_t)z*102400;
    if(z == 2) qe = nullptr;
  } else if(mode == 2){
    k0base = z*kchunk; Y += (size_t)z*102400; dobias = (z == 0);
  }
  int tx = tid & 15, ty = tid >> 4;
  int mload = tid >> 2;
  int k4 = (tid & 3) * 4;
  float acc[4][4] = {{0}};
  for(int k0=0; k0<kchunk; k0+=16){
    float4 xv = make_float4(0.f,0.f,0.f,0.f);
    int gm = bm + mload;
    if(gm < M){
      xv = *(const float4*)(X + (size_t)gm*Kstride + k0base + k0 + k4);
      if(qe){
        float4 pv = ld4(qe, (size_t)(gm>>2)*256 + k0base + k0 + k4, f);
        xv.x += pv.x; xv.y += pv.y; xv.z += pv.z; xv.w += pv.w;
      }
    }
    Xs[k4+0][mload] = xv.x; Xs[k4+1][mload] = xv.y;
    Xs[k4+2][mload] = xv.z; Xs[k4+3][mload] = xv.w;
    size_t wr = wo + (size_t)(bn + mload)*Kstride + k0base + k0 + k4;
    Ws[k4+0][mload] = ldf(W, wr,   f); Ws[k4+1][mload] = ldf(W, wr+1, f);
    Ws[k4+2][mload] = ldf(W, wr+2, f); Ws[k4+3][mload] = ldf(W, wr+3, f);
    __syncthreads();
    #pragma unroll
    for(int kk=0; kk<16; kk++){
      float a0=Xs[kk][ty*4+0], a1=Xs[kk][ty*4+1], a2=Xs[kk][ty*4+2], a3=Xs[kk][ty*4+3];
      float b0=Ws[kk][tx*4+0], b1=Ws[kk][tx*4+1], b2=Ws[kk][tx*4+2], b3=Ws[kk][tx*4+3];
      acc[0][0]+=a0*b0; acc[0][1]+=a0*b1; acc[0][2]+=a0*b2; acc[0][3]+=a0*b3;
      acc[1][0]+=a1*b0; acc[1][1]+=a1*b1; acc[1][2]+=a1*b2; acc[1][3]+=a1*b3;
      acc[2][0]+=a2*b0; acc[2][1]+=a2*b1; acc[2][2]+=a2*b2; acc[2][3]+=a2*b3;
      acc[3][0]+=a3*b0; acc[3][1]+=a3*b1; acc[3][2]+=a3*b2; acc[3][3]+=a3*b3;
    }
    __syncthreads();
  }
  #pragma unroll
  for(int i=0;i<4;i++){
    int m = bm + ty*4 + i;
    if(m >= M) continue;
    #pragma unroll
    for(int j=0;j<4;j++){
      int n = bn + tx*4 + j;
      float vv = acc[i][j] + ((dobias && bias) ? ldf(bias, bo + n, f) : 0.f);
      if(relu) vv = fmaxf(vv, 0.f);
      Y[(size_t)m*N + n] = vv;
    }
  }
}

// ---------- self-attention (fp32 K/V, small S) ----------
__global__ __launch_bounds__(64) void k_attn(
    float* __restrict__ out, const float* __restrict__ q,
    const float* __restrict__ k, const float* __restrict__ v,
    int B, int S, size_t bstride, size_t sstride, float scale)
{
  int lane = threadIdx.x;
  int l = blockIdx.x, h = blockIdx.y, b = blockIdx.z;
  const float4* qp = (const float4*)(q + ((size_t)(l*B+b))*256 + h*32);
  float4 qr[8];
  #pragma unroll
  for(int d=0; d<8; d++) qr[d] = qp[d];
  float m = -1e30f, lsum = 0.f;
  float acc[32];
  #pragma unroll
  for(int d=0; d<32; d++) acc[d] = 0.f;
  for(int s=lane; s<S; s+=64){
    const float4* kp = (const float4*)(k + b*bstride + (size_t)s*sstride + h*32);
    const float4* vp2 = (const float4*)(v + b*bstride + (size_t)s*sstride + h*32);
    float e = 0.f;
    #pragma unroll
    for(int d=0; d<8; d++){
      float4 kv = kp[d];
      e += qr[d].x*kv.x + qr[d].y*kv.y + qr[d].z*kv.z + qr[d].w*kv.w;
    }
    e *= scale;
    float nm = fmaxf(m, e);
    float ff = __expf(m - nm);
    float p = __expf(e - nm);
    lsum = lsum*ff + p;
    #pragma unroll
    for(int d=0; d<8; d++){
      float4 vv = vp2[d];
      acc[4*d+0] = acc[4*d+0]*ff + p*vv.x;
      acc[4*d+1] = acc[4*d+1]*ff + p*vv.y;
      acc[4*d+2] = acc[4*d+2]*ff + p*vv.z;
      acc[4*d+3] = acc[4*d+3]*ff + p*vv.w;
    }
    m = nm;
  }
  #pragma unroll
  for(int off=32; off>0; off>>=1){
    float om = __shfl_xor(m, off);
    float ol = __shfl_xor(lsum, off);
    float nm = fmaxf(m, om);
    float fa = __expf(m - nm), fb = __expf(om - nm);
    lsum = lsum*fa + ol*fb;
    #pragma unroll
    for(int d=0; d<32; d++){
      float oa = __shfl_xor(acc[d], off);
      acc[d] = acc[d]*fa + oa*fb;
    }
    m = nm;
  }
  if(lane == 0){
    float inv = 1.0f/lsum;
    float* op = out + ((size_t)(l*B+b))*256 + h*32;
    #pragma unroll
    for(int d=0; d<32; d++) op[d] = acc[d]*inv;
  }
}

// ---------- cross-attention via MFMA flash ----------
__global__ __launch_bounds__(256) void k_attn_x(
    float* __restrict__ part, const float* __restrict__ q,
    const __hip_bfloat16* __restrict__ k, const __hip_bfloat16* __restrict__ v,
    float scale)
{
  __shared__ float Om[4][16][33];
  __shared__ float Mm[4][16], Ll[4][16];
  const int tid = threadIdx.x, lane = tid & 63, wv = tid >> 6;
  const int quad = lane >> 4, l16 = lane & 15;
  const int qtile = blockIdx.x, h = blockIdx.y;
  const int b = blockIdx.z >> 2, chunk = blockIdx.z & 3;

  int l = qtile*16 + l16; if(l > 99) l = 99;
  const float* qp = q + ((size_t)(l*4 + b))*256 + h*32 + quad*8;
  union { ushort8 u; bf16x8 b; } qf;
  #pragma unroll
  for(int j=0;j<8;j++) qf.u[j] = f2b(qp[j]);

  const unsigned short* kb = (const unsigned short*)k + ((size_t)b*HW)*256 + h*32;
  const unsigned short* vb = (const unsigned short*)v + ((size_t)b*HW)*256 + h*32;

  float m = -1e30f, ls = 0.f;
  f32x4 oA = (f32x4){0.f,0.f,0.f,0.f};
  f32x4 oB = (f32x4){0.f,0.f,0.f,0.f};

  const int kb0 = chunk*1024 + wv*256;
  for(int it=0; it<4; it++){
    const int kbase = kb0 + it*64;
    f32x4 st[4];
    #pragma unroll
    for(int t=0;t<4;t++){
      union { ushort8 u; bf16x8 b; } kf;
      kf.u = *(const ushort8*)(kb + (size_t)(kbase + t*16 + l16)*256 + quad*8);
      st[t] = __builtin_amdgcn_mfma_f32_16x16x32_bf16(kf.b, qf.b,
              (f32x4){0.f,0.f,0.f,0.f}, 0, 0, 0);
    }
    float mx = -1e30f;
    #pragma unroll
    for(int t=0;t<4;t++){
      #pragma unroll
      for(int r=0;r<4;r++){ st[t][r] *= scale; mx = fmaxf(mx, st[t][r]); }
    }
    mx = fmaxf(mx, __shfl_xor(mx, 16));
    mx = fmaxf(mx, __shfl_xor(mx, 32));
    float nm = fmaxf(m, mx);
    float ff = __expf(m - nm);
    m = nm;
    ls *= ff;
    #pragma unroll
    for(int r=0;r<4;r++){
      float fr = __shfl(ff, quad*4 + r);
      oA[r] *= fr; oB[r] *= fr;
    }
    unsigned int pk[4][2];
    #pragma unroll
    for(int t=0;t<4;t++){
      float p0 = __expf(st[t][0]-m), p1 = __expf(st[t][1]-m);
      float p2 = __expf(st[t][2]-m), p3 = __expf(st[t][3]-m);
      ls += (p0+p1) + (p2+p3);
      pk[t][0] = (unsigned int)f2b(p0) | ((unsigned int)f2b(p1)<<16);
      pk[t][1] = (unsigned int)f2b(p2) | ((unsigned int)f2b(p3)<<16);
    }
    #pragma unroll
    for(int m2=0;m2<2;m2++){
      union { int w[4]; bf16x8 b; } pa;
      const int srcl = ((quad&1)*2)*16 + l16;
      #pragma unroll
      for(int w=0;w<4;w++){
        int sl = srcl + ((w>>1)<<4);
        int wa = __shfl((int)pk[m2*2  ][w&1], sl);
        int wb = __shfl((int)pk[m2*2+1][w&1], sl);
        pa.w[w] = (quad < 2) ? wa : wb;
      }
      const unsigned short* vrow = vb + (size_t)(kbase + m2*32 + quad*8)*256 + l16;
      union { ushort8 u; bf16x8 b; } va, vc;
      #pragma unroll
      for(int j=0;j<8;j++){
        va.u[j] = vrow[(size_t)j*256];
        vc.u[j] = vrow[(size_t)j*256 + 16];
      }
      oA = __builtin_amdgcn_mfma_f32_16x16x32_bf16(pa.b, va.b, oA, 0, 0, 0);
      oB = __builtin_amdgcn_mfma_f32_16x16x32_bf16(pa.b, vc.b, oB, 0, 0, 0);
    }
  }
  ls += __shfl_xor(ls, 16);
  ls += __shfl_xor(ls, 32);
  #pragma unroll
  for(int r=0;r<4;r++){
    Om[wv][quad*4+r][l16]    = oA[r];
    Om[wv][quad*4+r][16+l16] = oB[r];
  }
  if(lane < 16){ Mm[wv][lane] = m; Ll[wv][lane] = ls; }
  __syncthreads();
  if(wv == 0){
    const int qq = lane >> 2;
    float M = fmaxf(fmaxf(Mm[0][qq], Mm[1][qq]), fmaxf(Mm[2][qq], Mm[3][qq]));
    float f0 = __expf(Mm[0][qq]-M), f1 = __expf(Mm[1][qq]-M);
    float f2 = __expf(Mm[2][qq]-M), f3 = __expf(Mm[3][qq]-M);
    int lq = qtile*16 + qq;
    if(lq <= 99){
      float* pr = part + ((size_t)(((chunk*100 + lq)*8 + h)*4 + b))*36;
      #pragma unroll
      for(int i=0;i<8;i++){
        int dh = ((lane&3)<<3) + i;
        float O = Om[0][qq][dh]*f0 + Om[1][qq][dh]*f1
                + Om[2][qq][dh]*f2 + Om[3][qq][dh]*f3;
        pr[dh] = O;
      }
      if((lane & 3) == 0){
        float L = Ll[0][qq]*f0 + Ll[1][qq]*f1 + Ll[2][qq]*f2 + Ll[3][qq]*f3;
        pr[32] = M; pr[33] = L;
      }
    }
  }
}

// ---------- merge 4 S-chunk partials -> attout ----------
__global__ __launch_bounds__(256) void k_attn_xmrg(
    float* __restrict__ out, const float* __restrict__ part)
{
  const int l = blockIdx.x, tid = threadIdx.x;
  const int b = tid >> 6, h = (tid >> 3) & 7, dl = tid & 7;
  const float* p0 = part + ((size_t)(((0*100 + l)*8 + h)*4 + b))*36;
  float M = p0[32], L = p0[33];
  float4 A = *(const float4*)(p0 + dl*4);
  #pragma unroll
  for(int c=1; c<4; c++){
    const float* pc = part + ((size_t)(((c*100 + l)*8 + h)*4 + b))*36;
    float om = pc[32], ol = pc[33];
    float4 oa = *(const float4*)(pc + dl*4);
    float nm = fmaxf(M, om);
    float fa = __expf(M - nm), fb = __expf(om - nm);
    L = L*fa + ol*fb;
    A.x = A.x*fa + oa.x*fb; A.y = A.y*fa + oa.y*fb;
    A.z = A.z*fa + oa.z*fb; A.w = A.w*fa + oa.w*fb;
    M = nm;
  }
  float inv = 1.0f/L;
  *(float4*)(out + ((size_t)(l*4 + b))*256 + h*32 + dl*4) =
      make_float4(A.x*inv, A.y*inv, A.z*inv, A.w*inv);
}

// ---------- LayerNorm over C=256 ----------
__global__ __launch_bounds__(256) void k_ln(
    float* dst, const float* x, const float* t2, int nsl,
    vp g, vp bb, size_t go, const int* dflag)
{
  __shared__ float red[256];
  int f = *dflag;
  int c = threadIdx.x; int tok = blockIdx.x;
  float v = x[(size_t)tok*256 + c];
  if(t2){
    for(int s2=0; s2<nsl; s2++) v += t2[(size_t)s2*102400 + (size_t)tok*256 + c];
  }
  red[c] = v; __syncthreads();
  for(int s=128; s>0; s>>=1){ if(c<s) red[c] += red[c+s]; __syncthreads(); }
  float mu = red[0]*(1.f/256.f);
  __syncthreads();
  float dv = v - mu;
  red[c] = dv*dv; __syncthreads();
  for(int s=128; s>0; s>>=1){ if(c<s) red[c] += red[c+s]; __syncthreads(); }
  float var = red[0]*(1.f/256.f);
  float r = rsqrtf(var + 1e-5f);
  dst[(size_t)tok*256 + c] = dv*r*ldf(g, go+c, f) + ldf(bb, go+c, f);
}

__global__ void k_write_hs(void* out, const float* lnout, const int* dflag){
  int f = *dflag;
  int c = threadIdx.x; int tok = blockIdx.x; int l = tok >> 2; int b = tok & 3;
  float v = lnout[(size_t)tok*256 + c];
  size_t o = ((size_t)(b*100+l))*256 + c;
  if(f) ((float*)out)[o] = v;
  else  ((__hip_bfloat16*)out)[o] = __float2bfloat16(v);
}

extern "C" void kernel_launch(void* const* d_in, const int* in_sizes, int n_in,
                              void* d_out, int out_size, void* d_ws, size_t ws_size,
                              hipStream_t stream) {
  vp src       = d_in[0];
  vp query_emb = d_in[2];
  vp pos       = d_in[3];
  vp conva_w   = d_in[4];
  vp q_w = d_in[5];  vp q_b = d_in[6];
  vp k_w = d_in[7];  vp k_b = d_in[8];
  vp v_w = d_in[9];  vp v_b = d_in[10];
  vp gamma = d_in[11];
  vp convb_w = d_in[12];
  vp bneck_w = d_in[13];
  vp sa_in_w = d_in[14];  vp sa_in_b = d_in[15];
  vp sa_out_w = d_in[16]; vp sa_out_b = d_in[17];
  vp ca_in_w = d_in[18];  vp ca_in_b = d_in[19];
  vp ca_out_w = d_in[20]; vp ca_out_b = d_in[21];
  vp lin1_w = d_in[22];   vp lin1_b = d_in[23];
  vp lin2_w = d_in[24];   vp lin2_b = d_in[25];
  vp n1g = d_in[26]; vp n1b = d_in[27];
  vp n2g = d_in[28]; vp n2b = d_in[29];
  vp n3g = d_in[30]; vp n3b = d_in[31];
  vp normg = d_in[32]; vp normb = d_in[33];

  const size_t MEG = 1048576;
  float* ws   = (float*)d_ws;
  float* memf  = ws;                    // 4M floats (ping)
  float* xi    = ws + 4*MEG;            // 4M (pong; later mem_t)
  float* y64a  = ws + 8*MEG;            // 1M
  float* y64b  = ws + 9*MEG;            // 1M
  float* vb_   = ws + 10*MEG;           // 1M
  float* qb_   = ws + 11*MEG;           // 128K
  float* kb_   = ws + 11*MEG + 131072;  // 128K
  float* y256  = ws + 9*MEG;            // 4M (overlaps dead cc buffers)
  float* mem_t = xi;                    // decoder tokens
  __hip_bfloat16* kproj = (__hip_bfloat16*)memf;            // 16384x256 bf16
  __hip_bfloat16* vproj = (__hip_bfloat16*)(ws + 8*MEG);    // == kproj + 16777216 elems
  float* psum  = ws + 10*MEG;           // 819200 floats (K-split partials / attn_x partials)
  float* sm    = ws + 13*MEG + 262144;
  float* outq   = sm;
  float* qproj  = sm + 204800;
  float* kself  = sm + 307200;
  float* vself  = sm + 409600;
  float* attout = sm + 512000;
  float* t2     = sm + 614400;
  float* ffn1   = sm + 716800;
  float* lnout  = sm + 1536000;
  unsigned short* Wp = (unsigned short*)(ws + 15532032);
  int*   dflag  = (int*)(ws + 15532032 + 589824);

  const int NFULL = 4194304;
  const float scale = 0.17677669529663687f;

  k_detect<<<1, 256, 0, stream>>>(dflag, (const unsigned short*)src);
  k_cvt<<<4096, 256, 0, stream>>>((float4*)memf, src, NFULL/4, dflag);

  // ------------- encoder (mem ping-pongs memf<->xi; pos fused into conv staging) -------------
  float* cur = memf;
  float* nxt = xi;
  for(int i=0; i<6; i++){
    k_repack<<<72, 256, 0, stream>>>(Wp, conva_w, (size_t)i*147456, 256, 64, dflag);
    k_conv3x3_mfma<<<dim3(64,1,4), 256, 0, stream>>>(y64a, cur, nullptr, Wp, 256, 0, 64, 1, pos, dflag);
    for(int pass=0; pass<2; pass++){
      const float* cx = pass ? y64b : y64a;
      float* cy       = pass ? y64a : y64b;
      k_conv1x1_qkv<<<dim3(64,80,4), 64, 0, stream>>>(qb_, kb_, vb_, cx,
          q_w, (size_t)i*512,  q_b, (size_t)i*8,
          k_w, (size_t)i*512,  k_b, (size_t)i*8,
          v_w, (size_t)i*4096, v_b, (size_t)i*64, dflag);
      k_cc_fused<<<dim3(64,4), 256, 0, stream>>>(cy, vb_, qb_, kb_, cx, gamma, (size_t)i, dflag);
    }
    k_repack<<<72, 256, 0, stream>>>(Wp, convb_w, (size_t)i*147456, 64, 256, dflag);
    k_conv3x3_mfma<<<dim3(64,4,4), 256, 0, stream>>>(y256, y64a, nullptr, Wp, 64, 0, 256, 1, nullptr, dflag);
    k_repack<<<576, 256, 0, stream>>>(Wp, bneck_w, (size_t)i*1179648, 512, 256, dflag);
    k_conv3x3_mfma<<<dim3(64,4,4), 256, 0, stream>>>(nxt, cur, y256, Wp, 256, 256, 256, 0, pos, dflag);
    float* tmp = cur; cur = nxt; nxt = tmp;
  }
  // 6 layers (even) -> cur == memf here.

  // ------------- decoder prep: fused transpose + memory_2d write (before kproj overwrites memf) -------------
  k_finalize_mem<<<dim3(64,4,4), 256, 0, stream>>>(mem_t, d_out, cur, dflag);
  k_zero<<<400, 256, 0, stream>>>(outq, 102400);

  // ------------- decoder layers -------------
  for(int i=0; i<6; i++){
    size_t iw = (size_t)i*196608, ib = (size_t)i*768;
    size_t ow = (size_t)i*65536,  ob = (size_t)i*256;
    // self-attention: batched q/k/v projections (qe fused for q,k; not v)
    k_gemm<<<dim3(4,7,3), 256, 0, stream>>>(qproj, outq, sa_in_w, iw, sa_in_b, ib, query_emb, 400, 256, 256, 256, 1, 0, dflag);
    k_attn<<<dim3(100,8,4), 64, 0, stream>>>(attout, qproj, kself, vself,
        4, 100, (size_t)256, (size_t)1024, scale);
    // out-proj: 4-way K-split into psum, reduced in k_ln
    k_gemm<<<dim3(4,7,4), 256, 0, stream>>>(psum, attout, sa_out_w, ow, sa_out_b, ob, nullptr, 400, 256, 256, 64, 2, 0, dflag);
    k_ln<<<400, 256, 0, stream>>>(outq, outq, psum, 4, n1g, n1b, ob, dflag);
    // cross-attention: qe fused into qproj; k/v MFMA projections batched (z=2)
    k_gemm<<<dim3(4,7), 256, 0, stream>>>(qproj, outq, ca_in_w, iw, ca_in_b, ib, query_emb, 400, 256, 256, 256, 0, 0, dflag);
    k_gemm_mfma<<<dim3(4,256,2), 256, 0, stream>>>(kproj, mem_t, ca_in_w, iw+65536, ca_in_b, ib+256, pos, 16384, 256, 256, dflag);
    // MFMA flash cross-attention: partials into psum, then merge
    k_attn_x<<<dim3(7,8,16), 256, 0, stream>>>(psum, qproj, kproj, vproj, scale);
    k_attn_xmrg<<<100, 256, 0, stream>>>(attout, psum);
    k_gemm<<<dim3(4,7,4), 256, 0, stream>>>(psum, attout, ca_out_w, ow, ca_out_b, ob, nullptr, 400, 256, 256, 64, 2, 0, dflag);
    k_ln<<<400, 256, 0, stream>>>(outq, outq, psum, 4, n2g, n2b, ob, dflag);
    // FFN: ffn1 plain; ffn2 8-way K-split, reduced inside k_ln
    k_gemm<<<dim3(32,7), 256, 0, stream>>>(ffn1, outq, lin1_w, (size_t)i*524288, lin1_b, (size_t)i*2048, nullptr, 400, 2048, 256, 256, 0, 1, dflag);
    k_gemm<<<dim3(4,7,8), 256, 0, stream>>>(psum, ffn1, lin2_w, (size_t)i*524288, lin2_b, ob, nullptr, 400, 256, 2048, 256, 2, 0, dflag);
    k_ln<<<400, 256, 0, stream>>>(outq, outq, psum, 8, n3g, n3b, ob, dflag);
  }

  k_ln<<<400, 256, 0, stream>>>(lnout, outq, nullptr, 0, normg, normb, (size_t)0, dflag);
  k_write_hs<<<400, 256, 0, stream>>>(d_out, lnout, dflag);
}

// Round 12
// 3048.995 us; speedup vs baseline: 1.0765x; 1.0193x over previous
//
#include <hip/hip_runtime.h>
#include <hip/hip_bf16.h>

#define HW 4096
#define WD 64
#define HT 64
#define NEGV -1000000000.0f

typedef const void* vp;
typedef __attribute__((ext_vector_type(8))) short bf16x8;
typedef __attribute__((ext_vector_type(8))) unsigned short ushort8;
typedef __attribute__((ext_vector_type(4))) float f32x4;

__device__ __forceinline__ float b2f(__hip_bfloat16 v){ return __bfloat162float(v); }
__device__ __forceinline__ float ldf(vp p, size_t i, int f){
  return f ? ((const float*)p)[i] : b2f(((const __hip_bfloat16*)p)[i]);
}
__device__ __forceinline__ unsigned short f2b(float x){
  __hip_bfloat16 h = __float2bfloat16(x);
  return *reinterpret_cast<unsigned short*>(&h);
}
__device__ __forceinline__ float u2f(unsigned short u){
  union { unsigned int i; float f; } x; x.i = ((unsigned int)u) << 16; return x.f;
}
__device__ __forceinline__ float4 ld4(vp p, size_t i, int f){
  if(f) return *(const float4*)((const float*)p + i);
  ushort4 u = *(const ushort4*)((const unsigned short*)p + i);
  return make_float4(u2f(u.x), u2f(u.y), u2f(u.z), u2f(u.w));
}

// ---------- dtype detector ----------
__global__ void k_detect(int* flag, const unsigned short* p){
  __shared__ int cnt;
  if(threadIdx.x==0) cnt=0;
  __syncthreads();
  int c=0;
  for(int i=threadIdx.x; i<512; i+=256){
    int e = (p[i]>>7)&0xFF;
    if(e>150 || e<100) c++;
  }
  atomicAdd(&cnt, c);
  __syncthreads();
  if(threadIdx.x==0) *flag = (cnt>32) ? 1 : 0;  // 1 = fp32 inputs
}

// ---------- elementwise (vectorized x4) ----------
__global__ void k_cvt(float4* dst, vp src, int n4, const int* dflag){
  int f = *dflag;
  int i = blockIdx.x*256 + threadIdx.x;
  if(i<n4) dst[i] = ld4(src, (size_t)i*4, f);
}

__global__ void k_zero(float* p, int n){
  int i = blockIdx.x*256 + threadIdx.x;
  if(i<n) p[i] = 0.f;
}

// ---------- fused token transpose + memory_2d output write ----------
__global__ __launch_bounds__(256) void k_finalize_mem(
    float* __restrict__ mem_t, void* __restrict__ dout,
    const float* __restrict__ memf, const int* dflag)
{
  __shared__ float tile[64][65];
  const int f = *dflag;
  const int tid = threadIdx.x;
  const int s0 = blockIdx.x*64, c0t = blockIdx.y*64, b = blockIdx.z;
  const int sl = tid & 63, g4 = tid >> 6;
  #pragma unroll
  for(int p=0; p<16; p++){
    int cl = p*4 + g4;
    float v = memf[((size_t)(b*256 + c0t + cl))*HW + s0 + sl];
    tile[sl][cl] = v;
    size_t o = 102400 + ((size_t)(b*256 + c0t + cl))*HW + s0 + sl;
    if(f) ((float*)dout)[o] = v;
    else  ((__hip_bfloat16*)dout)[o] = __float2bfloat16(v);
  }
  __syncthreads();
  const int cl = tid & 63;
  #pragma unroll
  for(int p=0; p<16; p++){
    int s_local = p*4 + g4;
    mem_t[((size_t)(b*HW + s0 + s_local))*256 + c0t + cl] = tile[s_local][cl];
  }
}

// ---------- conv weight repack into A-fragment order ----------
__global__ void k_repack(unsigned short* Wp, vp w, size_t wo, int Cin, int Cout, const int* dflag){
  int f = *dflag;
  int slab = blockIdx.x;
  int tap = slab % 9; int t2 = slab / 9;
  int nch = Cin >> 5; int ch = t2 % nch; int cotile = t2 / nch;
  for(int e=threadIdx.x; e<2048; e+=256){
    int col = e >> 5, ciL = e & 31;
    size_t co = cotile*64 + col, ci = ch*32 + ciL;
    float v = ldf(w, wo + (co*Cin + ci)*9 + tap, f);
    Wp[(size_t)slab*2048 + e] = f2b(v);
  }
}

// ---------- 3x3 conv via MFMA implicit GEMM (repacked weights) ----------
// SWZ=1: 64-ushort swizzled rows (bank-conflict fix; pays off when nch is
// large, e.g. bneck nch=16). SWZ=0: 40-ushort padded rows (lower overhead;
// better for small-nch convs where staging VALU dominates).
template<int SWZ>
__global__ __launch_bounds__(256) void k_conv3x3_mfma(
    float* __restrict__ out, const float* __restrict__ in1, const float* __restrict__ in2,
    const unsigned short* __restrict__ Wp, int Cin1, int Cin2, int Cout, int relu,
    vp posp, const int* dflag)
{
  constexpr int RS = SWZ ? 64 : 40;
  __shared__ __attribute__((aligned(16))) unsigned short Xs[3*66*RS];
  const int tid  = threadIdx.x;
  const int lane = tid & 63;
  const int wv   = tid >> 6;
  const int quad = lane >> 4;
  const int l16  = lane & 15;
  const int h    = blockIdx.x;
  const int cotile = blockIdx.y;
  const int b    = blockIdx.z;
  const int Cin  = Cin1 + Cin2;
  const int nch  = Cin >> 5;
  const int f    = posp ? *dflag : 0;

  auto idx = [](int row, int blk){
    if(SWZ) return row*64 + (((blk ^ ((row ^ (row>>3)) & 7)) << 3));
    else    return row*40 + blk*8;
  };

  if(tid < 96){
    int kh = tid>>5, ci = tid&31;
    int cblk = ci>>3, coff = ci&7;
    Xs[idx(kh*66 + 0,  cblk) + coff] = 0;
    Xs[idx(kh*66 + 65, cblk) + coff] = 0;
  }

  f32x4 acc[4];
  #pragma unroll
  for(int nt=0; nt<4; nt++) acc[nt] = (f32x4){0.f,0.f,0.f,0.f};

  const unsigned short* wlane = Wp + ((size_t)cotile*nch)*9*2048 + (wv*16+l16)*32 + quad*8;

  for(int ch=0; ch<nch; ch++){
    __syncthreads();
    #pragma unroll
    for(int it=0; it<6; it++){
      int t   = it*256 + tid;
      int kh  = t >> 9;
      int rem = t & 511;
      int ci  = rem >> 4;
      int w4  = (rem & 15) << 2;
      int r   = h + kh - 1;
      float4 xv = make_float4(0.f,0.f,0.f,0.f);
      int cg = ch*32 + ci;
      if(r >= 0 && r < HT){
        const float* srcp = (cg < Cin1) ? in1 + ((size_t)(b*Cin1+cg))*HW
                                        : in2 + ((size_t)(b*Cin2+(cg-Cin1)))*HW;
        xv = *(const float4*)(srcp + r*WD + w4);
        if(posp && cg < Cin1){
          float4 pv = ld4(posp, ((size_t)(b*256+cg))*HW + (size_t)r*WD + w4, f);
          xv.x += pv.x; xv.y += pv.y; xv.z += pv.z; xv.w += pv.w;
        }
      }
      int rowb = kh*66 + w4 + 1;
      int cblk = ci>>3, coff = ci&7;
      Xs[idx(rowb+0, cblk) + coff] = f2b(xv.x);
      Xs[idx(rowb+1, cblk) + coff] = f2b(xv.y);
      Xs[idx(rowb+2, cblk) + coff] = f2b(xv.z);
      Xs[idx(rowb+3, cblk) + coff] = f2b(xv.w);
    }
    __syncthreads();
    const unsigned short* wch = wlane + (size_t)ch*9*2048;
    #pragma unroll
    for(int tap=0; tap<9; tap++){
      const int kh = tap/3, kw = tap%3;
      bf16x8 af = *(const bf16x8*)(wch + tap*2048);
      #pragma unroll
      for(int nt=0; nt<4; nt++){
        bf16x8 bfr = *(const bf16x8*)&Xs[idx(kh*66 + nt*16 + l16 + kw, quad)];
        acc[nt] = __builtin_amdgcn_mfma_f32_16x16x32_bf16(af, bfr, acc[nt], 0, 0, 0);
      }
    }
  }
  #pragma unroll
  for(int nt=0; nt<4; nt++){
    #pragma unroll
    for(int r=0; r<4; r++){
      float vv = acc[nt][r];
      if(relu) vv = fmaxf(vv, 0.f);
      out[((size_t)(b*Cout + cotile*64 + wv*16 + quad*4 + r))*HW + h*WD + nt*16 + l16] = vv;
    }
  }
}

// ---------- MFMA GEMM with bf16 output ----------
__global__ __launch_bounds__(256) void k_gemm_mfma(
    __hip_bfloat16* __restrict__ Y, const float* __restrict__ X, vp W, size_t wo,
    vp bias, size_t bo, vp pos2, int M, int N, int K, const int* dflag)
{
  __shared__ __attribute__((aligned(16))) unsigned short Xs[64*40];
  __shared__ __attribute__((aligned(16))) unsigned short Ws[64*40];
  if(blockIdx.z){ wo += 65536; bo += 256; pos2 = nullptr; Y += 16777216; }
  const int f = *dflag;
  const int tid = threadIdx.x;
  const int bn = blockIdx.x*64, bm = blockIdx.y*64;
  const int lane = tid & 63, wv = tid >> 6, quad = lane >> 4, l16 = lane & 15;
  const int row = tid >> 2, kq = (tid & 3) * 8;

  f32x4 acc[4];
  #pragma unroll
  for(int mt=0; mt<4; mt++) acc[mt] = (f32x4){0.f,0.f,0.f,0.f};

  for(int k0=0; k0<K; k0+=32){
    __syncthreads();
    {
      int gm = bm + row;
      const float* xp = X + (size_t)gm*K + k0 + kq;
      float4 xa = *(const float4*)xp;
      float4 xb = *(const float4*)(xp+4);
      if(pos2){
        int b = gm >> 12, s = gm & 4095;
        size_t pb = ((size_t)(b*256 + k0 + kq))*HW + s;
        xa.x += ldf(pos2, pb,      f); xa.y += ldf(pos2, pb+HW,   f);
        xa.z += ldf(pos2, pb+2*HW, f); xa.w += ldf(pos2, pb+3*HW, f);
        xb.x += ldf(pos2, pb+4*HW, f); xb.y += ldf(pos2, pb+5*HW, f);
        xb.z += ldf(pos2, pb+6*HW, f); xb.w += ldf(pos2, pb+7*HW, f);
      }
      ushort8 xo;
      xo[0]=f2b(xa.x); xo[1]=f2b(xa.y); xo[2]=f2b(xa.z); xo[3]=f2b(xa.w);
      xo[4]=f2b(xb.x); xo[5]=f2b(xb.y); xo[6]=f2b(xb.z); xo[7]=f2b(xb.w);
      *(ushort8*)&Xs[row*40 + kq] = xo;
    }
    {
      size_t wr = wo + (size_t)(bn + row)*K + k0 + kq;
      ushort8 wo8;
      if(f){
        const float* wp2 = (const float*)W + wr;
        float4 wa = *(const float4*)wp2;
        float4 wb = *(const float4*)(wp2+4);
        wo8[0]=f2b(wa.x); wo8[1]=f2b(wa.y); wo8[2]=f2b(wa.z); wo8[3]=f2b(wa.w);
        wo8[4]=f2b(wb.x); wo8[5]=f2b(wb.y); wo8[6]=f2b(wb.z); wo8[7]=f2b(wb.w);
      } else {
        wo8 = *(const ushort8*)((const unsigned short*)W + wr);
      }
      *(ushort8*)&Ws[row*40 + kq] = wo8;
    }
    __syncthreads();
    bf16x8 bfr = *(const bf16x8*)&Ws[(wv*16 + l16)*40 + quad*8];
    #pragma unroll
    for(int mt=0; mt<4; mt++){
      bf16x8 af = *(const bf16x8*)&Xs[(mt*16 + l16)*40 + quad*8];
      acc[mt] = __builtin_amdgcn_mfma_f32_16x16x32_bf16(af, bfr, acc[mt], 0, 0, 0);
    }
  }
  const int n = bn + wv*16 + l16;
  const float bv = ldf(bias, bo + n, f);
  #pragma unroll
  for(int mt=0; mt<4; mt++){
    #pragma unroll
    for(int r=0; r<4; r++){
      int m = bm + mt*16 + quad*4 + r;
      Y[(size_t)m*N + n] = __float2bfloat16(acc[mt][r] + bv);
    }
  }
}

// ---------- merged 1x1 convs for criss-cross q/k/v (Cin=64) ----------
__global__ __launch_bounds__(64) void k_conv1x1_qkv(
    float* __restrict__ qout, float* __restrict__ kout, float* __restrict__ vout,
    const float* __restrict__ in,
    vp qw, size_t qwo, vp qb, size_t qbo,
    vp kw, size_t kwo, vp kb2, size_t kbo,
    vp vw, size_t vwo, vp vb2, size_t vbo, const int* dflag)
{
  __shared__ float wl[64];
  int f = *dflag;
  int tid = threadIdx.x; int cy = blockIdx.y; int b = blockIdx.z;
  int p = blockIdx.x*64 + tid;

  vp w; size_t wo2; vp bi; size_t bo2; float* out; int co; int oc;
  if(cy < 8)      { w=qw; wo2=qwo; bi=qb;  bo2=qbo; out=qout; co=cy;    oc=8;  }
  else if(cy < 16){ w=kw; wo2=kwo; bi=kb2; bo2=kbo; out=kout; co=cy-8;  oc=8;  }
  else            { w=vw; wo2=vwo; bi=vb2; bo2=vbo; out=vout; co=cy-16; oc=64; }

  wl[tid] = ldf(w, wo2 + (size_t)co*64 + tid, f);
  __syncthreads();
  float acc = ldf(bi, bo2 + co, f);
  for(int c=0; c<64; c++) acc += in[((size_t)(b*64+c))*HW + p]*wl[c];
  out[((size_t)(b*oc+co))*HW + p] = acc;
}

// ---------- fused criss-cross: energies + softmax + aggregation ----------
__global__ __launch_bounds__(256) void k_cc_fused(
    float* __restrict__ out, const float* __restrict__ v,
    const float* __restrict__ q, const float* __restrict__ k,
    const float* __restrict__ x, vp gamma, size_t go, const int* dflag)
{
  __shared__ float E[64*129];
  __shared__ float Vh[64*65];
  __shared__ float qs[8*64];
  __shared__ float kh[8*64];
  __shared__ float red[4*64];
  __shared__ float Mw[64], Sw[64];
  const int tid = threadIdx.x, lane = tid & 63, wv = tid >> 6;
  const int h = blockIdx.x, b = blockIdx.y;
  const int f = *dflag;

  for(int cc=wv; cc<8; cc+=4){
    qs[cc*64+lane] = q[((size_t)(b*8+cc))*HW + h*WD + lane];
    kh[cc*64+lane] = k[((size_t)(b*8+cc))*HW + h*WD + lane];
  }
  for(int cc=wv; cc<64; cc+=4)
    Vh[cc*65+lane] = v[((size_t)(b*64+cc))*HW + h*WD + lane];
  __syncthreads();

  {
    const int w = lane;
    for(int jt=0; jt<32; jt++){
      int j = wv*32 + jt;
      float e = 0.f;
      if(j < 64){
        const float* kcol = k + ((size_t)(b*8))*HW + (size_t)j*WD + w;
        #pragma unroll
        for(int c=0;c<8;c++) e += qs[c*64+w]*kcol[(size_t)c*HW];
        if(j == h) e += NEGV;
      } else {
        int jj = j - 64;
        #pragma unroll
        for(int c=0;c<8;c++) e += qs[c*64+w]*kh[c*64+jj];
      }
      E[w*129 + j] = e;
    }
  }
  __syncthreads();
  {
    const int w = lane;
    float mx = -1e30f;
    for(int jt=0; jt<32; jt++) mx = fmaxf(mx, E[w*129 + wv*32 + jt]);
    red[wv*64+w] = mx;
  }
  __syncthreads();
  if(wv==0){
    int w = lane;
    Mw[w] = fmaxf(fmaxf(red[w], red[64+w]), fmaxf(red[128+w], red[192+w]));
  }
  __syncthreads();
  {
    const int w = lane;
    float mx = Mw[w], s = 0.f;
    for(int jt=0; jt<32; jt++){
      int j = wv*32 + jt;
      float p = __expf(E[w*129+j] - mx);
      E[w*129+j] = p;
      s += p;
    }
    red[wv*64+w] = s;
  }
  __syncthreads();
  if(wv==0){
    int w = lane;
    Sw[w] = 1.0f/(red[w]+red[64+w]+red[128+w]+red[192+w]);
  }
  __syncthreads();
  {
    const int w = lane;
    const int c0 = wv*16;
    float acc[16];
    #pragma unroll
    for(int i=0;i<16;i++) acc[i] = 0.f;
    const float* vbase = v + ((size_t)(b*64 + c0))*HW + w;
    for(int j=0;j<64;j++){
      float p = E[w*129 + j];
      const float* vcol = vbase + (size_t)j*WD;
      #pragma unroll
      for(int i=0;i<16;i++) acc[i] += vcol[(size_t)i*HW]*p;
    }
    for(int j=0;j<64;j++){
      float p = E[w*129 + 64 + j];
      #pragma unroll
      for(int i=0;i<16;i++) acc[i] += Vh[(c0+i)*65 + j]*p;
    }
    float g = ldf(gamma, go, f);
    float inv = Sw[w];
    #pragma unroll
    for(int i=0;i<16;i++){
      size_t idx = ((size_t)(b*64 + c0 + i))*HW + (size_t)h*WD + w;
      out[idx] = g*(acc[i]*inv) + x[idx];
    }
  }
}

// ---------- fp32 GEMM (small M) ----------
__global__ __launch_bounds__(256) void k_gemm(
    float* __restrict__ Y, const float* __restrict__ X, vp W, size_t wo,
    vp bias, size_t bo, vp qe, int M, int N, int Kstride, int kchunk,
    int mode, int relu, const int* dflag)
{
  __shared__ float Xs[16][68];
  __shared__ float Ws[16][68];
  int f = *dflag;
  int tid = threadIdx.x;
  int bn = blockIdx.x*64, bm = blockIdx.y*64;
  int z = blockIdx.z;
  int k0base = 0, dobias = 1;
  if(mode == 1){
    wo += (size_t)z*65536; bo += (size_t)z*256; Y += (size_t)z*102400;
    if(z == 2) qe = nullptr;
  } else if(mode == 2){
    k0base = z*kchunk; Y += (size_t)z*102400; dobias = (z == 0);
  }
  int tx = tid & 15, ty = tid >> 4;
  int mload = tid >> 2;
  int k4 = (tid & 3) * 4;
  float acc[4][4] = {{0}};
  for(int k0=0; k0<kchunk; k0+=16){
    float4 xv = make_float4(0.f,0.f,0.f,0.f);
    int gm = bm + mload;
    if(gm < M){
      xv = *(const float4*)(X + (size_t)gm*Kstride + k0base + k0 + k4);
      if(qe){
        float4 pv = ld4(qe, (size_t)(gm>>2)*256 + k0base + k0 + k4, f);
        xv.x += pv.x; xv.y += pv.y; xv.z += pv.z; xv.w += pv.w;
      }
    }
    Xs[k4+0][mload] = xv.x; Xs[k4+1][mload] = xv.y;
    Xs[k4+2][mload] = xv.z; Xs[k4+3][mload] = xv.w;
    size_t wr = wo + (size_t)(bn + mload)*Kstride + k0base + k0 + k4;
    Ws[k4+0][mload] = ldf(W, wr,   f); Ws[k4+1][mload] = ldf(W, wr+1, f);
    Ws[k4+2][mload] = ldf(W, wr+2, f); Ws[k4+3][mload] = ldf(W, wr+3, f);
    __syncthreads();
    #pragma unroll
    for(int kk=0; kk<16; kk++){
      float a0=Xs[kk][ty*4+0], a1=Xs[kk][ty*4+1], a2=Xs[kk][ty*4+2], a3=Xs[kk][ty*4+3];
      float b0=Ws[kk][tx*4+0], b1=Ws[kk][tx*4+1], b2=Ws[kk][tx*4+2], b3=Ws[kk][tx*4+3];
      acc[0][0]+=a0*b0; acc[0][1]+=a0*b1; acc[0][2]+=a0*b2; acc[0][3]+=a0*b3;
      acc[1][0]+=a1*b0; acc[1][1]+=a1*b1; acc[1][2]+=a1*b2; acc[1][3]+=a1*b3;
      acc[2][0]+=a2*b0; acc[2][1]+=a2*b1; acc[2][2]+=a2*b2; acc[2][3]+=a2*b3;
      acc[3][0]+=a3*b0; acc[3][1]+=a3*b1; acc[3][2]+=a3*b2; acc[3][3]+=a3*b3;
    }
    __syncthreads();
  }
  #pragma unroll
  for(int i=0;i<4;i++){
    int m = bm + ty*4 + i;
    if(m >= M) continue;
    #pragma unroll
    for(int j=0;j<4;j++){
      int n = bn + tx*4 + j;
      float vv = acc[i][j] + ((dobias && bias) ? ldf(bias, bo + n, f) : 0.f);
      if(relu) vv = fmaxf(vv, 0.f);
      Y[(size_t)m*N + n] = vv;
    }
  }
}

// ---------- self-attention (fp32 K/V, small S) ----------
__global__ __launch_bounds__(64) void k_attn(
    float* __restrict__ out, const float* __restrict__ q,
    const float* __restrict__ k, const float* __restrict__ v,
    int B, int S, size_t bstride, size_t sstride, float scale)
{
  int lane = threadIdx.x;
  int l = blockIdx.x, h = blockIdx.y, b = blockIdx.z;
  const float4* qp = (const float4*)(q + ((size_t)(l*B+b))*256 + h*32);
  float4 qr[8];
  #pragma unroll
  for(int d=0; d<8; d++) qr[d] = qp[d];
  float m = -1e30f, lsum = 0.f;
  float acc[32];
  #pragma unroll
  for(int d=0; d<32; d++) acc[d] = 0.f;
  for(int s=lane; s<S; s+=64){
    const float4* kp = (const float4*)(k + b*bstride + (size_t)s*sstride + h*32);
    const float4* vp2 = (const float4*)(v + b*bstride + (size_t)s*sstride + h*32);
    float e = 0.f;
    #pragma unroll
    for(int d=0; d<8; d++){
      float4 kv = kp[d];
      e += qr[d].x*kv.x + qr[d].y*kv.y + qr[d].z*kv.z + qr[d].w*kv.w;
    }
    e *= scale;
    float nm = fmaxf(m, e);
    float ff = __expf(m - nm);
    float p = __expf(e - nm);
    lsum = lsum*ff + p;
    #pragma unroll
    for(int d=0; d<8; d++){
      float4 vv = vp2[d];
      acc[4*d+0] = acc[4*d+0]*ff + p*vv.x;
      acc[4*d+1] = acc[4*d+1]*ff + p*vv.y;
      acc[4*d+2] = acc[4*d+2]*ff + p*vv.z;
      acc[4*d+3] = acc[4*d+3]*ff + p*vv.w;
    }
    m = nm;
  }
  #pragma unroll
  for(int off=32; off>0; off>>=1){
    float om = __shfl_xor(m, off);
    float ol = __shfl_xor(lsum, off);
    float nm = fmaxf(m, om);
    float fa = __expf(m - nm), fb = __expf(om - nm);
    lsum = lsum*fa + ol*fb;
    #pragma unroll
    for(int d=0; d<32; d++){
      float oa = __shfl_xor(acc[d], off);
      acc[d] = acc[d]*fa + oa*fb;
    }
    m = nm;
  }
  if(lane == 0){
    float inv = 1.0f/lsum;
    float* op = out + ((size_t)(l*B+b))*256 + h*32;
    #pragma unroll
    for(int d=0; d<32; d++) op[d] = acc[d]*inv;
  }
}

// ---------- cross-attention via MFMA flash ----------
__global__ __launch_bounds__(256) void k_attn_x(
    float* __restrict__ part, const float* __restrict__ q,
    const __hip_bfloat16* __restrict__ k, const __hip_bfloat16* __restrict__ v,
    float scale)
{
  __shared__ float Om[4][16][33];
  __shared__ float Mm[4][16], Ll[4][16];
  const int tid = threadIdx.x, lane = tid & 63, wv = tid >> 6;
  const int quad = lane >> 4, l16 = lane & 15;
  const int qtile = blockIdx.x, h = blockIdx.y;
  const int b = blockIdx.z >> 2, chunk = blockIdx.z & 3;

  int l = qtile*16 + l16; if(l > 99) l = 99;
  const float* qp = q + ((size_t)(l*4 + b))*256 + h*32 + quad*8;
  union { ushort8 u; bf16x8 b; } qf;
  #pragma unroll
  for(int j=0;j<8;j++) qf.u[j] = f2b(qp[j]);

  const unsigned short* kb = (const unsigned short*)k + ((size_t)b*HW)*256 + h*32;
  const unsigned short* vb = (const unsigned short*)v + ((size_t)b*HW)*256 + h*32;

  float m = -1e30f, ls = 0.f;
  f32x4 oA = (f32x4){0.f,0.f,0.f,0.f};
  f32x4 oB = (f32x4){0.f,0.f,0.f,0.f};

  const int kb0 = chunk*1024 + wv*256;
  for(int it=0; it<4; it++){
    const int kbase = kb0 + it*64;
    f32x4 st[4];
    #pragma unroll
    for(int t=0;t<4;t++){
      union { ushort8 u; bf16x8 b; } kf;
      kf.u = *(const ushort8*)(kb + (size_t)(kbase + t*16 + l16)*256 + quad*8);
      st[t] = __builtin_amdgcn_mfma_f32_16x16x32_bf16(kf.b, qf.b,
              (f32x4){0.f,0.f,0.f,0.f}, 0, 0, 0);
    }
    float mx = -1e30f;
    #pragma unroll
    for(int t=0;t<4;t++){
      #pragma unroll
      for(int r=0;r<4;r++){ st[t][r] *= scale; mx = fmaxf(mx, st[t][r]); }
    }
    mx = fmaxf(mx, __shfl_xor(mx, 16));
    mx = fmaxf(mx, __shfl_xor(mx, 32));
    float nm = fmaxf(m, mx);
    float ff = __expf(m - nm);
    m = nm;
    ls *= ff;
    #pragma unroll
    for(int r=0;r<4;r++){
      float fr = __shfl(ff, quad*4 + r);
      oA[r] *= fr; oB[r] *= fr;
    }
    unsigned int pk[4][2];
    #pragma unroll
    for(int t=0;t<4;t++){
      float p0 = __expf(st[t][0]-m), p1 = __expf(st[t][1]-m);
      float p2 = __expf(st[t][2]-m), p3 = __expf(st[t][3]-m);
      ls += (p0+p1) + (p2+p3);
      pk[t][0] = (unsigned int)f2b(p0) | ((unsigned int)f2b(p1)<<16);
      pk[t][1] = (unsigned int)f2b(p2) | ((unsigned int)f2b(p3)<<16);
    }
    #pragma unroll
    for(int m2=0;m2<2;m2++){
      union { int w[4]; bf16x8 b; } pa;
      const int srcl = ((quad&1)*2)*16 + l16;
      #pragma unroll
      for(int w=0;w<4;w++){
        int sl = srcl + ((w>>1)<<4);
        int wa = __shfl((int)pk[m2*2  ][w&1], sl);
        int wb = __shfl((int)pk[m2*2+1][w&1], sl);
        pa.w[w] = (quad < 2) ? wa : wb;
      }
      const unsigned short* vrow = vb + (size_t)(kbase + m2*32 + quad*8)*256 + l16;
      union { ushort8 u; bf16x8 b; } va, vc;
      #pragma unroll
      for(int j=0;j<8;j++){
        va.u[j] = vrow[(size_t)j*256];
        vc.u[j] = vrow[(size_t)j*256 + 16];
      }
      oA = __builtin_amdgcn_mfma_f32_16x16x32_bf16(pa.b, va.b, oA, 0, 0, 0);
      oB = __builtin_amdgcn_mfma_f32_16x16x32_bf16(pa.b, vc.b, oB, 0, 0, 0);
    }
  }
  ls += __shfl_xor(ls, 16);
  ls += __shfl_xor(ls, 32);
  #pragma unroll
  for(int r=0;r<4;r++){
    Om[wv][quad*4+r][l16]    = oA[r];
    Om[wv][quad*4+r][16+l16] = oB[r];
  }
  if(lane < 16){ Mm[wv][lane] = m; Ll[wv][lane] = ls; }
  __syncthreads();
  if(wv == 0){
    const int qq = lane >> 2;
    float M = fmaxf(fmaxf(Mm[0][qq], Mm[1][qq]), fmaxf(Mm[2][qq], Mm[3][qq]));
    float f0 = __expf(Mm[0][qq]-M), f1 = __expf(Mm[1][qq]-M);
    float f2 = __expf(Mm[2][qq]-M), f3 = __expf(Mm[3][qq]-M);
    int lq = qtile*16 + qq;
    if(lq <= 99){
      float* pr = part + ((size_t)(((chunk*100 + lq)*8 + h)*4 + b))*36;
      #pragma unroll
      for(int i=0;i<8;i++){
        int dh = ((lane&3)<<3) + i;
        float O = Om[0][qq][dh]*f0 + Om[1][qq][dh]*f1
                + Om[2][qq][dh]*f2 + Om[3][qq][dh]*f3;
        pr[dh] = O;
      }
      if((lane & 3) == 0){
        float L = Ll[0][qq]*f0 + Ll[1][qq]*f1 + Ll[2][qq]*f2 + Ll[3][qq]*f3;
        pr[32] = M; pr[33] = L;
      }
    }
  }
}

// ---------- merge 4 S-chunk partials -> attout ----------
__global__ __launch_bounds__(256) void k_attn_xmrg(
    float* __restrict__ out, const float* __restrict__ part)
{
  const int l = blockIdx.x, tid = threadIdx.x;
  const int b = tid >> 6, h = (tid >> 3) & 7, dl = tid & 7;
  const float* p0 = part + ((size_t)(((0*100 + l)*8 + h)*4 + b))*36;
  float M = p0[32], L = p0[33];
  float4 A = *(const float4*)(p0 + dl*4);
  #pragma unroll
  for(int c=1; c<4; c++){
    const float* pc = part + ((size_t)(((c*100 + l)*8 + h)*4 + b))*36;
    float om = pc[32], ol = pc[33];
    float4 oa = *(const float4*)(pc + dl*4);
    float nm = fmaxf(M, om);
    float fa = __expf(M - nm), fb = __expf(om - nm);
    L = L*fa + ol*fb;
    A.x = A.x*fa + oa.x*fb; A.y = A.y*fa + oa.y*fb;
    A.z = A.z*fa + oa.z*fb; A.w = A.w*fa + oa.w*fb;
    M = nm;
  }
  float inv = 1.0f/L;
  *(float4*)(out + ((size_t)(l*4 + b))*256 + h*32 + dl*4) =
      make_float4(A.x*inv, A.y*inv, A.z*inv, A.w*inv);
}

// ---------- LayerNorm over C=256 ----------
__global__ __launch_bounds__(256) void k_ln(
    float* dst, const float* x, const float* t2, int nsl,
    vp g, vp bb, size_t go, const int* dflag)
{
  __shared__ float red[256];
  int f = *dflag;
  int c = threadIdx.x; int tok = blockIdx.x;
  float v = x[(size_t)tok*256 + c];
  if(t2){
    for(int s2=0; s2<nsl; s2++) v += t2[(size_t)s2*102400 + (size_t)tok*256 + c];
  }
  red[c] = v; __syncthreads();
  for(int s=128; s>0; s>>=1){ if(c<s) red[c] += red[c+s]; __syncthreads(); }
  float mu = red[0]*(1.f/256.f);
  __syncthreads();
  float dv = v - mu;
  red[c] = dv*dv; __syncthreads();
  for(int s=128; s>0; s>>=1){ if(c<s) red[c] += red[c+s]; __syncthreads(); }
  float var = red[0]*(1.f/256.f);
  float r = rsqrtf(var + 1e-5f);
  dst[(size_t)tok*256 + c] = dv*r*ldf(g, go+c, f) + ldf(bb, go+c, f);
}

__global__ void k_write_hs(void* out, const float* lnout, const int* dflag){
  int f = *dflag;
  int c = threadIdx.x; int tok = blockIdx.x; int l = tok >> 2; int b = tok & 3;
  float v = lnout[(size_t)tok*256 + c];
  size_t o = ((size_t)(b*100+l))*256 + c;
  if(f) ((float*)out)[o] = v;
  else  ((__hip_bfloat16*)out)[o] = __float2bfloat16(v);
}

extern "C" void kernel_launch(void* const* d_in, const int* in_sizes, int n_in,
                              void* d_out, int out_size, void* d_ws, size_t ws_size,
                              hipStream_t stream) {
  vp src       = d_in[0];
  vp query_emb = d_in[2];
  vp pos       = d_in[3];
  vp conva_w   = d_in[4];
  vp q_w = d_in[5];  vp q_b = d_in[6];
  vp k_w = d_in[7];  vp k_b = d_in[8];
  vp v_w = d_in[9];  vp v_b = d_in[10];
  vp gamma = d_in[11];
  vp convb_w = d_in[12];
  vp bneck_w = d_in[13];
  vp sa_in_w = d_in[14];  vp sa_in_b = d_in[15];
  vp sa_out_w = d_in[16]; vp sa_out_b = d_in[17];
  vp ca_in_w = d_in[18];  vp ca_in_b = d_in[19];
  vp ca_out_w = d_in[20]; vp ca_out_b = d_in[21];
  vp lin1_w = d_in[22];   vp lin1_b = d_in[23];
  vp lin2_w = d_in[24];   vp lin2_b = d_in[25];
  vp n1g = d_in[26]; vp n1b = d_in[27];
  vp n2g = d_in[28]; vp n2b = d_in[29];
  vp n3g = d_in[30]; vp n3b = d_in[31];
  vp normg = d_in[32]; vp normb = d_in[33];

  const size_t MEG = 1048576;
  float* ws   = (float*)d_ws;
  float* memf  = ws;                    // 4M floats (ping)
  float* xi    = ws + 4*MEG;            // 4M (pong; later mem_t)
  float* y64a  = ws + 8*MEG;            // 1M
  float* y64b  = ws + 9*MEG;            // 1M
  float* vb_   = ws + 10*MEG;           // 1M
  float* qb_   = ws + 11*MEG;           // 128K
  float* kb_   = ws + 11*MEG + 131072;  // 128K
  float* y256  = ws + 9*MEG;            // 4M (overlaps dead cc buffers)
  float* mem_t = xi;                    // decoder tokens
  __hip_bfloat16* kproj = (__hip_bfloat16*)memf;            // 16384x256 bf16
  __hip_bfloat16* vproj = (__hip_bfloat16*)(ws + 8*MEG);    // == kproj + 16777216 elems
  float* psum  = ws + 10*MEG;           // 819200 floats (K-split partials / attn_x partials)
  float* sm    = ws + 13*MEG + 262144;
  float* outq   = sm;
  float* qproj  = sm + 204800;
  float* kself  = sm + 307200;
  float* vself  = sm + 409600;
  float* attout = sm + 512000;
  float* t2     = sm + 614400;
  float* ffn1   = sm + 716800;
  float* lnout  = sm + 1536000;
  unsigned short* Wp = (unsigned short*)(ws + 15532032);
  int*   dflag  = (int*)(ws + 15532032 + 589824);

  const int NFULL = 4194304;
  const float scale = 0.17677669529663687f;

  k_detect<<<1, 256, 0, stream>>>(dflag, (const unsigned short*)src);
  k_cvt<<<4096, 256, 0, stream>>>((float4*)memf, src, NFULL/4, dflag);

  // ------------- encoder (mem ping-pongs memf<->xi; pos fused into conv staging) -------------
  float* cur = memf;
  float* nxt = xi;
  for(int i=0; i<6; i++){
    k_repack<<<72, 256, 0, stream>>>(Wp, conva_w, (size_t)i*147456, 256, 64, dflag);
    k_conv3x3_mfma<0><<<dim3(64,1,4), 256, 0, stream>>>(y64a, cur, nullptr, Wp, 256, 0, 64, 1, pos, dflag);
    for(int pass=0; pass<2; pass++){
      const float* cx = pass ? y64b : y64a;
      float* cy       = pass ? y64a : y64b;
      k_conv1x1_qkv<<<dim3(64,80,4), 64, 0, stream>>>(qb_, kb_, vb_, cx,
          q_w, (size_t)i*512,  q_b, (size_t)i*8,
          k_w, (size_t)i*512,  k_b, (size_t)i*8,
          v_w, (size_t)i*4096, v_b, (size_t)i*64, dflag);
      k_cc_fused<<<dim3(64,4), 256, 0, stream>>>(cy, vb_, qb_, kb_, cx, gamma, (size_t)i, dflag);
    }
    k_repack<<<72, 256, 0, stream>>>(Wp, convb_w, (size_t)i*147456, 64, 256, dflag);
    k_conv3x3_mfma<0><<<dim3(64,4,4), 256, 0, stream>>>(y256, y64a, nullptr, Wp, 64, 0, 256, 1, nullptr, dflag);
    k_repack<<<576, 256, 0, stream>>>(Wp, bneck_w, (size_t)i*1179648, 512, 256, dflag);
    k_conv3x3_mfma<1><<<dim3(64,4,4), 256, 0, stream>>>(nxt, cur, y256, Wp, 256, 256, 256, 0, pos, dflag);
    float* tmp = cur; cur = nxt; nxt = tmp;
  }
  // 6 layers (even) -> cur == memf here.

  // ------------- decoder prep: fused transpose + memory_2d write (before kproj overwrites memf) -------------
  k_finalize_mem<<<dim3(64,4,4), 256, 0, stream>>>(mem_t, d_out, cur, dflag);
  k_zero<<<400, 256, 0, stream>>>(outq, 102400);

  // ------------- decoder layers -------------
  for(int i=0; i<6; i++){
    size_t iw = (size_t)i*196608, ib = (size_t)i*768;
    size_t ow = (size_t)i*65536,  ob = (size_t)i*256;
    // self-attention: batched q/k/v projections (qe fused for q,k; not v)
    k_gemm<<<dim3(4,7,3), 256, 0, stream>>>(qproj, outq, sa_in_w, iw, sa_in_b, ib, query_emb, 400, 256, 256, 256, 1, 0, dflag);
    k_attn<<<dim3(100,8,4), 64, 0, stream>>>(attout, qproj, kself, vself,
        4, 100, (size_t)256, (size_t)1024, scale);
    // out-proj: 4-way K-split into psum, reduced in k_ln
    k_gemm<<<dim3(4,7,4), 256, 0, stream>>>(psum, attout, sa_out_w, ow, sa_out_b, ob, nullptr, 400, 256, 256, 64, 2, 0, dflag);
    k_ln<<<400, 256, 0, stream>>>(outq, outq, psum, 4, n1g, n1b, ob, dflag);
    // cross-attention: qe fused into qproj; k/v MFMA projections batched (z=2)
    k_gemm<<<dim3(4,7), 256, 0, stream>>>(qproj, outq, ca_in_w, iw, ca_in_b, ib, query_emb, 400, 256, 256, 256, 0, 0, dflag);
    k_gemm_mfma<<<dim3(4,256,2), 256, 0, stream>>>(kproj, mem_t, ca_in_w, iw+65536, ca_in_b, ib+256, pos, 16384, 256, 256, dflag);
    // MFMA flash cross-attention: partials into psum, then merge
    k_attn_x<<<dim3(7,8,16), 256, 0, stream>>>(psum, qproj, kproj, vproj, scale);
    k_attn_xmrg<<<100, 256, 0, stream>>>(attout, psum);
    k_gemm<<<dim3(4,7,4), 256, 0, stream>>>(psum, attout, ca_out_w, ow, ca_out_b, ob, nullptr, 400, 256, 256, 64, 2, 0, dflag);
    k_ln<<<400, 256, 0, stream>>>(outq, outq, psum, 4, n2g, n2b, ob, dflag);
    // FFN: ffn1 plain; ffn2 8-way K-split, reduced inside k_ln
    k_gemm<<<dim3(32,7), 256, 0, stream>>>(ffn1, outq, lin1_w, (size_t)i*524288, lin1_b, (size_t)i*2048, nullptr, 400, 2048, 256, 256, 0, 1, dflag);
    k_gemm<<<dim3(4,7,8), 256, 0, stream>>>(psum, ffn1, lin2_w, (size_t)i*524288, lin2_b, ob, nullptr, 400, 256, 2048, 256, 2, 0, dflag);
    k_ln<<<400, 256, 0, stream>>>(outq, outq, psum, 8, n3g, n3b, ob, dflag);
  }

  k_ln<<<400, 256, 0, stream>>>(lnout, outq, nullptr, 0, normg, normb, (size_t)0, dflag);
  k_write_hs<<<400, 256, 0, stream>>>(d_out, lnout, dflag);
}